// Round 9
// baseline (503.810 us; speedup 1.0000x reference)
//
#include <hip/hip_runtime.h>
#include <hip/hip_bf16.h>

// LightGCN forward on MI355X — round 18.
// r17 post-mortem: fused sort+layer1 landed as predicted (121.5us), but
//   occupancy 46.6% (27.7KB LDS -> 5 blocks/CU = 20 waves/CU + residency
//   tail) vs spmm_csr's 79% — it pays +21us for the same gather wall with
//   half the latency-hiding waves.
// r18: RPB 64->32 (NF=128, CAPF=1792, +11.5 sigma): LDS 14.6KB -> 8 blocks/CU
//   = 32 waves/CU (wave cap). e[14]->e[7] staging. Bit-fields re-derived
//   (fine7=x>>23, lr5=x&31; gather offset mask unchanged). ws ~128.8MB <=
//   proven 136.5MB floor. scatter1 prefetches cols/vals during histogram.

#define N_USERS  100000
#define N_ITEMS  50000
#define N_TOTAL  150000          // N_USERS + N_ITEMS
#define D        64
#define NNZ      6400000
#define BATCH    4096
#define NELEM    (N_TOTAL * D)   // 9,600,000

#define NC       37              // coarse buckets (4096 rows each)
#define CROWS    4096
#define CAPC     194600          // coarse capacity (mean 174763 + 48 sigma);
                                 // also sized so X >= A+B+C (57.6MB aliasing)
#define S1C      4096            // scatter1 chunk (fits 32KB LDS stage)
#define S1EB     ((NNZ + S1C - 1) / S1C)       // 1563
#define S2C      4096
#define NCH2     ((CAPC + S2C - 1) / S2C)      // 48 chunks per coarse region
#define NF       128             // fine buckets per coarse (32 rows each)
#define RPB      32
#define NBUK     (NC * NF)       // 4736 fine buckets
#define CAPF     1792            // fine capacity = mean 1365 + 11.5 sigma

__device__ __forceinline__ float bf2f(unsigned short h) {
    return __uint_as_float(((unsigned int)h) << 16);
}

// ---------- zero cursors ----------
__global__ void lgcn_zero(int* __restrict__ cur1, int* __restrict__ cur2) {
    int i = threadIdx.x;
    if (i < NC) cur1[i] = 0;
    for (int j = i; j < NBUK; j += 256) cur2[j] = 0;
}

// ---------- pass 1: COO -> 37 coarse buckets, LDS sort + coalesced flush ----
// X pair: x = (row_in_coarse<<18) | col  (12b + 18b), y = val bits
__global__ void __launch_bounds__(256)
lgcn_scatter1(const int*   __restrict__ rows,
              const int*   __restrict__ cols,
              const float* __restrict__ vals,
              int*         __restrict__ cur1,
              int2*        __restrict__ X) {
    __shared__ int2 buf[S1C];              // 32 KB
    __shared__ unsigned char bk[S1C];      // 4 KB (bucket of slot)
    __shared__ int h[NC], ls[NC], gb[NC];
    int tid = threadIdx.x;
    int s = blockIdx.x * S1C;
    int n = NNZ - s; if (n > S1C) n = S1C;
    int r[16], c16[16], v16[16];

    if (tid < NC) h[tid] = 0;
    __syncthreads();
    #pragma unroll
    for (int k = 0; k < 16; k++) {         // coalesced load + histogram
        int i = tid + k * 256;
        if (i < n) {
            r[k]   = rows[s + i];
            c16[k] = cols[s + i];
            v16[k] = __float_as_int(vals[s + i]);
            atomicAdd(&h[r[k] >> 12], 1);
        } else r[k] = -1;
    }
    __syncthreads();
    if (tid == 0) {                        // serial scan over 37 buckets
        int acc = 0;
        for (int i = 0; i < NC; i++) { ls[i] = acc; acc += h[i]; }
    }
    if (tid < NC) gb[tid] = h[tid] ? atomicAdd(&cur1[tid], h[tid]) : 0;
    __syncthreads();
    if (tid < NC) h[tid] = 0;              // reuse as local cursor
    __syncthreads();
    #pragma unroll
    for (int k = 0; k < 16; k++) {         // place into bucket-ordered LDS
        if (r[k] >= 0) {
            int c = r[k] >> 12;
            int rank = atomicAdd(&h[c], 1);
            int slot = ls[c] + rank;
            int2 p;
            p.x = ((r[k] & 4095) << 18) | c16[k];
            p.y = v16[k];
            buf[slot] = p;
            bk[slot] = (unsigned char)c;
        }
    }
    __syncthreads();
    for (int j = tid; j < n; j += 256) {   // coalesced flush (runs ~110 entries)
        int c = bk[j];
        int o = gb[c] + j - ls[c];
        X[(o < CAPC) ? ((size_t)c * CAPC + o) : ((size_t)NC * CAPC)] = buf[j];
    }
}

// ---------- pass 2: coarse -> 128 fine buckets, LDS sort + coalesced flush ----
// Y pair: x = (col18 << 7) | lr5  (pre-scaled column: x & ~127 = row byte off)
__global__ void __launch_bounds__(256)
lgcn_scatter2(const int2* __restrict__ X,
              const int*  __restrict__ cur1,
              int*        __restrict__ cur2,
              int2*       __restrict__ Y) {
    __shared__ int2 buf[S2C];              // 32 KB
    __shared__ unsigned char bk[S2C];      // 4 KB
    __shared__ int h[NF], ls[NF], gb[NF];
    int c = blockIdx.x / NCH2;
    int ch = blockIdx.x % NCH2;
    int cnt_c = cur1[c]; if (cnt_c > CAPC) cnt_c = CAPC;
    int s = ch * S2C;
    int n = cnt_c - s; if (n > S2C) n = S2C;
    if (n <= 0) return;                    // uniform per block
    int tid = threadIdx.x;
    size_t base = (size_t)c * CAPC + s;
    int2 e[16];

    if (tid < NF) h[tid] = 0;
    __syncthreads();
    #pragma unroll
    for (int k = 0; k < 16; k++) {         // register-stage + histogram
        int i = tid + k * 256;
        if (i < n) {
            e[k] = X[base + i];
            atomicAdd(&h[e[k].x >> 23], 1);   // fine7 = lr12 >> 5
        } else e[k].x = -1;                   // x >= 0 for valid (30-bit)
    }
    __syncthreads();
    if (tid == 0) {
        int acc = 0;
        for (int i = 0; i < NF; i++) { ls[i] = acc; acc += h[i]; }
    }
    if (tid < NF) gb[tid] = h[tid] ? atomicAdd(&cur2[c * NF + tid], h[tid]) : 0;
    __syncthreads();
    if (tid < NF) h[tid] = 0;
    __syncthreads();
    #pragma unroll
    for (int k = 0; k < 16; k++) {
        if (e[k].x >= 0) {
            int f = e[k].x >> 23;
            int rank = atomicAdd(&h[f], 1);
            int slot = ls[f] + rank;
            int2 q;
            q.x = ((e[k].x & 0x3FFFF) << 7) | ((e[k].x >> 18) & 31);  // col<<7|lr5
            q.y = e[k].y;
            buf[slot] = q;
            bk[slot] = (unsigned char)f;
        }
    }
    __syncthreads();
    for (int j = tid; j < n; j += 256) {   // coalesced flush (runs ~32 entries)
        int f = bk[j];
        int o = gb[f] + j - ls[f];
        Y[(o < CAPF) ? ((size_t)(c * NF + f) * CAPF + o)
                     : ((size_t)NBUK * CAPF)] = buf[j];
    }
}

// ---------- init A = bf16(concat(user,item)) (after pass 2: A aliases X) ------
__global__ void lgcn_init_A(const float* __restrict__ user_emb,
                            const float* __restrict__ item_emb,
                            unsigned short* __restrict__ A) {
    int i = blockIdx.x * blockDim.x + threadIdx.x;
    if (i < NELEM) {
        float v = (i < N_USERS * D) ? user_emb[i] : item_emb[i - N_USERS * D];
        __hip_bfloat16 b = __float2bfloat16(v);   // RNE
        A[i] = *(unsigned short*)&b;
    }
}

// ---------- fused: per-bucket row sort + CSR emit + sorted-Y writeback +
//            SpMM layer 1 computed from LDS pairs (wave owns 8 rows) --------
__global__ void __launch_bounds__(256)
lgcn_spmm_sort(int2* __restrict__ Y,
               const int* __restrict__ cur2,
               int* __restrict__ row_ptr,
               int* __restrict__ row_cnt,
               const unsigned short* __restrict__ cur,
               unsigned short* __restrict__ nxt) {
    __shared__ int2 buf[CAPF + 2];     // 14.3 KB -> 8 blocks/CU (wave cap)
    __shared__ int  h[RPB];
    __shared__ int  base[RPB];
    int tid = threadIdx.x;
    int fb = blockIdx.x;
    size_t start = (size_t)fb * CAPF;
    int cnt = cur2[fb]; if (cnt > CAPF) cnt = CAPF;

    // register-stage load + per-row histogram
    int2 e[7];                         // ceil(1792/256) = 7
    if (tid < RPB) h[tid] = 0;
    __syncthreads();
    #pragma unroll
    for (int k = 0; k < 7; k++) {
        int i = tid + k * 256;
        if (i < cnt) {
            e[k] = Y[start + i];
            atomicAdd(&h[e[k].x & 31], 1);
        } else e[k].x = -1;            // valid x >= 0 (25-bit)
    }
    __syncthreads();

    // exclusive scan of h[0..31]
    int v = (tid < RPB) ? h[tid] : 0;
    int sum = v;
    #pragma unroll
    for (int off = 1; off < RPB; off <<= 1) {
        if (tid < RPB) base[tid] = sum;
        __syncthreads();
        if (tid >= off && tid < RPB) sum += base[tid - off];
        __syncthreads();
    }
    if (tid < RPB) {
        int excl = sum - v;
        base[tid] = excl;
        int gr = (fb >> 7) * CROWS + (fb & 127) * RPB + tid;
        if (gr < N_TOTAL) {
            row_ptr[gr] = (int)start + excl;
            row_cnt[gr] = v;
        }
        h[tid] = 0;                    // reuse as per-row cursor
    }
    __syncthreads();

    // place regs -> row-sorted LDS
    #pragma unroll
    for (int k = 0; k < 7; k++) {
        if (e[k].x >= 0) {
            int lr = e[k].x & 31;
            int rank = atomicAdd(&h[lr], 1);
            buf[base[lr] + rank] = e[k];
        }
    }
    __syncthreads();

    // coalesced sorted writeback (layer 2 reads this)
    for (int i = tid; i < cnt; i += 256) Y[start + i] = buf[i];

    // ---- SpMM layer 1 from LDS pairs: wave w owns rows w*8 .. w*8+7 ----
    int wave = tid >> 6, lane = tid & 63;
    int halfid = lane >> 5, hl = lane & 31;
    const char* __restrict__ curb = (const char*)cur + hl * 4;
    for (int lr = wave * 8; lr < wave * 8 + 8; lr++) {
        int rs = base[lr];
        int rc = h[lr];                // == row count after placement
        float sA = 0.f, sB = 0.f;
        int jj = 0;
        for (; jj + 8 <= rc; jj += 8) {            // unguarded dual-edge bodies
            #pragma unroll
            for (int k = 0; k < 4; k++) {
                int2 q = buf[rs + jj + 2 * k + halfid];   // ds_read broadcast
                float v2 = __int_as_float(q.y);
                unsigned off = (unsigned)q.x & 0xFFFFFF80u;
                unsigned u = *(const unsigned*)(curb + off);
                sA = fmaf(v2, __uint_as_float(u << 16), sA);
                sB = fmaf(v2, __uint_as_float(u & 0xFFFF0000u), sB);
            }
        }
        for (; jj < rc; jj += 2) {                 // guarded tail (<=4 iters)
            int2 q = buf[rs + jj + halfid];        // may overread 1 (padded)
            float v2 = __int_as_float(q.y);
            unsigned off = (unsigned)q.x & 0xFFFFFF80u;
            if (jj + halfid >= rc) { v2 = 0.f; off = 0; }
            unsigned u = *(const unsigned*)(curb + off);
            sA = fmaf(v2, __uint_as_float(u << 16), sA);
            sB = fmaf(v2, __uint_as_float(u & 0xFFFF0000u), sB);
        }
        sA += __shfl_xor(sA, 32, 64);
        sB += __shfl_xor(sB, 32, 64);
        int gr = (fb >> 7) * CROWS + (fb & 127) * RPB + lr;
        if (halfid == 0 && gr < N_TOTAL) {
            __hip_bfloat16 a = __float2bfloat16(sA);   // RNE
            __hip_bfloat16 b = __float2bfloat16(sB);
            unsigned int lo = *(unsigned short*)&a;
            unsigned int hi = *(unsigned short*)&b;
            ((unsigned int*)nxt)[gr * 32 + hl] = lo | (hi << 16);
        }
    }
}

// ---------- SpMM: wave per row, dual-edge, LDS-staged, 16-edge unroll ----------
__global__ void __launch_bounds__(256)
lgcn_spmm_csr(const int2* __restrict__ pairs,
              const int*  __restrict__ row_ptr,
              const int*  __restrict__ row_cnt,
              const unsigned short* __restrict__ cur,
              unsigned short* __restrict__ nxt) {
    __shared__ int2 stage[4][64];
    int t = blockIdx.x * blockDim.x + threadIdx.x;
    int r = t >> 6;
    int lane = t & 63;
    if (r >= N_TOTAL) return;
    int halfid = lane >> 5;
    int hl = lane & 31;
    const char* __restrict__ curb = (const char*)cur + hl * 4;  // lane-folded
    int2* st = stage[threadIdx.x >> 6];
    int start = row_ptr[r];
    int cnt   = row_cnt[r];
    float sA = 0.f, sB = 0.f;
    for (int base = 0; base < cnt; base += 64) {
        int idx = base + lane;
        int2 p = {0, 0};
        if (idx < cnt) p = pairs[start + idx];     // coalesced dwordx2
        st[lane] = p;                              // per-wave slice, no barrier
        int m = cnt - base; if (m > 64) m = 64;
        for (int jj = 0; jj < m; jj += 16) {       // 16 edges per body
            #pragma unroll
            for (int k = 0; k < 8; k++) {
                int2 q = st[jj + 2 * k + halfid];  // ds_read_b64 broadcast
                float v = __int_as_float(q.y);     // 0 beyond cnt
                unsigned off = (unsigned)q.x & 0xFFFFFF80u;   // col*128
                unsigned u = *(const unsigned*)(curb + off);
                sA = fmaf(v, __uint_as_float(u << 16), sA);
                sB = fmaf(v, __uint_as_float(u & 0xFFFF0000u), sB);
            }
        }
    }
    sA += __shfl_xor(sA, 32, 64);
    sB += __shfl_xor(sB, 32, 64);
    if (halfid == 0) {
        __hip_bfloat16 a = __float2bfloat16(sA);   // RNE
        __hip_bfloat16 b = __float2bfloat16(sB);
        unsigned int lo = *(unsigned short*)&a;
        unsigned int hi = *(unsigned short*)&b;
        ((unsigned int*)nxt)[r * 32 + hl] = lo | (hi << 16);  // half-wave 128B
    }
}

// ---------- layer 3 at sampled rows only: e3[s,:] = (A @ E2)[row(s),:] (f32) ----
__global__ void __launch_bounds__(256)
lgcn_spmm_sampled(const int2* __restrict__ pairs,
                  const int*  __restrict__ row_ptr,
                  const int*  __restrict__ row_cnt,
                  const unsigned short* __restrict__ cur,
                  const int* __restrict__ users,
                  const int* __restrict__ items,
                  float* __restrict__ e3) {
    __shared__ int2 stage[4][64];
    int t = blockIdx.x * blockDim.x + threadIdx.x;
    int s = t >> 6;
    int lane = t & 63;
    if (s >= 2 * BATCH) return;
    int r = (s < BATCH) ? users[s] : (N_USERS + items[s - BATCH]);
    const char* __restrict__ curb = (const char*)cur + lane * 2;  // bf16 dim
    int2* st = stage[threadIdx.x >> 6];
    int start = row_ptr[r];
    int cnt   = row_cnt[r];
    float sum0 = 0.f, sum1 = 0.f;
    for (int base = 0; base < cnt; base += 64) {
        int idx = base + lane;
        int2 p = {0, 0};
        if (idx < cnt) p = pairs[start + idx];
        st[lane] = p;
        int m = cnt - base; if (m > 64) m = 64;
        for (int j = 0; j < m; j += 16) {
            #pragma unroll
            for (int k = 0; k < 16; k++) {
                int2 q = st[j + k];                // broadcast
                float v = __int_as_float(q.y);     // 0 beyond cnt
                unsigned off = (unsigned)q.x & 0xFFFFFF80u;
                unsigned short u = *(const unsigned short*)(curb + off);
                if (k & 1) sum1 = fmaf(v, bf2f(u), sum1);
                else       sum0 = fmaf(v, bf2f(u), sum0);
            }
        }
    }
    e3[s * D + lane] = sum0 + sum1;
}

// ---------- dot: gamma = <E0+E1+E2+E3>_u . <E0+E1+E2+E3>_i / 16 ----------
__global__ void lgcn_dot(const float* __restrict__ user_emb,
                         const float* __restrict__ item_emb,
                         const unsigned short* __restrict__ E1,
                         const unsigned short* __restrict__ E2,
                         const float* __restrict__ e3,
                         const int* __restrict__ users,
                         const int* __restrict__ items,
                         float* __restrict__ out) {
    int t = blockIdx.x * blockDim.x + threadIdx.x;
    int b = t >> 6;
    int d = t & 63;
    if (b < BATCH) {
        int u  = users[b];
        int it = items[b];
        int ur = u * D + d;
        int ir = (N_USERS + it) * D + d;
        float au = user_emb[ur] + bf2f(E1[ur]) + bf2f(E2[ur]) + e3[b * D + d];
        float ai = item_emb[it * D + d] + bf2f(E1[ir]) + bf2f(E2[ir])
                 + e3[(BATCH + b) * D + d];
        float p = au * ai;
        #pragma unroll
        for (int off = 32; off; off >>= 1) p += __shfl_down(p, off, 64);
        if (d == 0) out[b] = p * (1.0f / 16.0f);
    }
}

// ---------- round-1 fallback (atomic scatter) if ws too small ----------
__global__ void lgcn_init_fb(const float* __restrict__ user_emb,
                             const float* __restrict__ item_emb,
                             float* __restrict__ acc,
                             float* __restrict__ cur,
                             float* __restrict__ nxt) {
    int i = blockIdx.x * blockDim.x + threadIdx.x;
    if (i < NELEM) {
        float v = (i < N_USERS * D) ? user_emb[i] : item_emb[i - N_USERS * D];
        acc[i] = v; cur[i] = v; nxt[i] = 0.0f;
    }
}
__global__ void lgcn_spmm_fb(const int* __restrict__ rows,
                             const int* __restrict__ cols,
                             const float* __restrict__ vals,
                             const float* __restrict__ cur,
                             float* __restrict__ nxt) {
    long long t = (long long)blockIdx.x * blockDim.x + threadIdx.x;
    int e = (int)(t >> 6);
    int d = (int)(t & 63);
    if (e < NNZ) {
        float x = cur[cols[e] * D + d];
        unsafeAtomicAdd(&nxt[rows[e] * D + d], vals[e] * x);
    }
}
__global__ void lgcn_accum_fb(float* __restrict__ acc,
                              const float* __restrict__ src,
                              float* __restrict__ to_zero) {
    int i = blockIdx.x * blockDim.x + threadIdx.x;
    if (i < NELEM) {
        acc[i] += src[i];
        if (to_zero) to_zero[i] = 0.0f;
    }
}
__global__ void lgcn_dot_fb(const float* __restrict__ acc,
                            const int* __restrict__ users,
                            const int* __restrict__ items,
                            float* __restrict__ out) {
    int t = blockIdx.x * blockDim.x + threadIdx.x;
    int b = t >> 6;
    int d = t & 63;
    if (b < BATCH) {
        int u  = users[b];
        int it = items[b];
        float p = acc[u * D + d] * acc[(N_USERS + it) * D + d];
        #pragma unroll
        for (int off = 32; off; off >>= 1) p += __shfl_down(p, off, 64);
        if (d == 0) out[b] = p * (1.0f / 16.0f);
    }
}

extern "C" void kernel_launch(void* const* d_in, const int* in_sizes, int n_in,
                              void* d_out, int out_size, void* d_ws, size_t ws_size,
                              hipStream_t stream) {
    const float* user_emb = (const float*)d_in[0];
    const float* item_emb = (const float*)d_in[1];
    const int*   edge_row = (const int*)d_in[2];
    const int*   edge_col = (const int*)d_in[3];
    const float* edge_val = (const float*)d_in[4];
    const int*   users    = (const int*)d_in[5];
    const int*   items    = (const int*)d_in[6];
    float*       out      = (float*)d_out;

    const int TPB = 256;
    int init_blocks = (NELEM + TPB - 1) / TPB;
    int spmm_blocks = (N_TOTAL * 64 + TPB - 1) / TPB;       // wave per row
    int samp_blocks = (2 * BATCH * 64 + TPB - 1) / TPB;     // wave per sampled row
    int dot_blocks  = (BATCH * 64 + TPB - 1) / TPB;

    // workspace layout (~128.8MB <= proven 136.5MB floor):
    //   X (coarse pairs, +1 sink) — dead after pass 2; A,B,C bf16 ALL alias it
    //     (CAPC sized so X bytes >= 3*NELEM*2 = 57.6MB)
    //   Y (fine pairs, +1 sink)   — row-sorted in the fused kernel
    //   e3 f32, cursors, row_ptr/row_cnt
    int2* X = (int2*)d_ws;                              // NC*CAPC + 1
    int2* Y = X + (size_t)NC * CAPC + 1;                // NBUK*CAPF + 1
    float* e3 = (float*)(Y + (size_t)NBUK * CAPF + 1);  // 2*BATCH*D
    int* cur1 = (int*)(e3 + 2 * BATCH * D);             // NC
    int* cur2 = cur1 + NC;                              // NBUK
    int* row_ptr = cur2 + NBUK;                         // NBUK*RPB
    int* row_cnt = row_ptr + NBUK * RPB;                // NBUK*RPB
    size_t req = (size_t)((char*)(row_cnt + NBUK * RPB) - (char*)d_ws);
    unsigned short* A = (unsigned short*)X;             // alias: init after pass 2
    unsigned short* B = A + NELEM;                      // alias
    unsigned short* C = B + NELEM;                      // alias: 57.6MB <= X bytes

    if (ws_size < req && ws_size >= (size_t)3 * NELEM * 4) {
        // fallback: round-1 atomic path (needs only 3*NELEM floats)
        float* acc = (float*)d_ws;
        float* Af  = acc + NELEM;
        float* Bf  = Af + NELEM;
        long long st = (long long)NNZ * 64;
        int sb = (int)((st + TPB - 1) / TPB);
        lgcn_init_fb<<<init_blocks, TPB, 0, stream>>>(user_emb, item_emb, acc, Af, Bf);
        lgcn_spmm_fb<<<sb, TPB, 0, stream>>>(edge_row, edge_col, edge_val, Af, Bf);
        lgcn_accum_fb<<<init_blocks, TPB, 0, stream>>>(acc, Bf, Af);
        lgcn_spmm_fb<<<sb, TPB, 0, stream>>>(edge_row, edge_col, edge_val, Bf, Af);
        lgcn_accum_fb<<<init_blocks, TPB, 0, stream>>>(acc, Af, Bf);
        lgcn_spmm_fb<<<sb, TPB, 0, stream>>>(edge_row, edge_col, edge_val, Af, Bf);
        lgcn_accum_fb<<<init_blocks, TPB, 0, stream>>>(acc, Bf, nullptr);
        lgcn_dot_fb<<<dot_blocks, TPB, 0, stream>>>(acc, users, items, out);
        return;
    }

    // two-level radix binning (LDS-sorted, coalesced flush)
    lgcn_zero<<<1, TPB, 0, stream>>>(cur1, cur2);
    lgcn_scatter1<<<S1EB, TPB, 0, stream>>>(edge_row, edge_col, edge_val, cur1, X);
    lgcn_scatter2<<<NC * NCH2, TPB, 0, stream>>>(X, cur1, cur2, Y);

    // E0 bf16 (A aliases dead X region)
    lgcn_init_A<<<init_blocks, TPB, 0, stream>>>(user_emb, item_emb, A);

    // fused: row sort + CSR emit + sorted-Y writeback + layer 1 from LDS
    lgcn_spmm_sort<<<NBUK, TPB, 0, stream>>>(Y, cur2, row_ptr, row_cnt, A, B);

    // layer 2 full width (bf16); layer 3 only at sampled rows (f32)
    lgcn_spmm_csr<<<spmm_blocks, TPB, 0, stream>>>(Y, row_ptr, row_cnt, B, C);
    lgcn_spmm_sampled<<<samp_blocks, TPB, 0, stream>>>(Y, row_ptr, row_cnt, C,
                                                       users, items, e3);

    // gamma
    lgcn_dot<<<dot_blocks, TPB, 0, stream>>>(user_emb, item_emb, B, C, e3,
                                             users, items, out);
}

// Round 11
// 460.422 us; speedup vs baseline: 1.0942x; 1.0942x over previous
//
#include <hip/hip_runtime.h>
#include <hip/hip_bf16.h>

// LightGCN forward on MI355X — round 20 (= r19 resubmit; r10 bench was an
//   infra failure "container failed twice", no profile/verdict — same as r3,
//   which passed on identical resubmit. r19 re-audited: CAPF=3200 is +9
//   sigma (P(overflow)~3e-16, sink-guarded anyway); init_A indexing exact;
//   ws ~121.5MB).
// r18 post-mortem: RPB 32 regressed spmm_sort 121.5->177us. Same VALU-busy
//   TIME (45us) both rounds => pure added stall; VGPR 44->20 means the
//   4-unrolled gather results couldn't stay live -> per-wave MLP ~4x down.
// r19/r20: r17 structure (465us proven) + two isolated deltas:
//   (a) CAPF 3456->3200: spmm_sort LDS 25.6KB -> 6 blocks/CU (24 waves/CU)
//       with ZERO code-structure change — clean occupancy test.
//   (b) init_A vectorized (2x float4 -> uint4 of 8 bf16), G13.

#define N_USERS  100000
#define N_ITEMS  50000
#define N_TOTAL  150000          // N_USERS + N_ITEMS
#define D        64
#define NNZ      6400000
#define BATCH    4096
#define NELEM    (N_TOTAL * D)   // 9,600,000

#define NC       37              // coarse buckets (4096 rows each)
#define CROWS    4096
#define CAPC     194600          // coarse capacity (mean 174763 + 48 sigma);
                                 // also sized so X >= A+B+C (57.6MB aliasing)
#define S1C      4096            // scatter1 chunk (fits 32KB LDS stage)
#define S1EB     ((NNZ + S1C - 1) / S1C)       // 1563
#define S2C      4096
#define NCH2     ((CAPC + S2C - 1) / S2C)      // 48 chunks per coarse region
#define NF       64              // fine buckets per coarse (64 rows each)
#define RPB      64
#define NBUK     (NC * NF)       // 2368 fine buckets
#define CAPF     3200            // fine capacity = mean 2731 + 9 sigma
                                 // (est. true max ~2937 for the fixed seed)

__device__ __forceinline__ float bf2f(unsigned short h) {
    return __uint_as_float(((unsigned int)h) << 16);
}
__device__ __forceinline__ unsigned short f2bf(float f) {
    __hip_bfloat16 b = __float2bfloat16(f);   // RNE
    return *(unsigned short*)&b;
}

// ---------- zero cursors ----------
__global__ void lgcn_zero(int* __restrict__ cur1, int* __restrict__ cur2) {
    int i = threadIdx.x;
    if (i < NC) cur1[i] = 0;
    for (int j = i; j < NBUK; j += 256) cur2[j] = 0;
}

// ---------- pass 1: COO -> 37 coarse buckets, LDS sort + coalesced flush ----
// X pair: x = (row_in_coarse<<18) | col  (12b + 18b), y = val bits
__global__ void __launch_bounds__(256)
lgcn_scatter1(const int*   __restrict__ rows,
              const int*   __restrict__ cols,
              const float* __restrict__ vals,
              int*         __restrict__ cur1,
              int2*        __restrict__ X) {
    __shared__ int2 buf[S1C];              // 32 KB
    __shared__ unsigned char bk[S1C];      // 4 KB (bucket of slot)
    __shared__ int h[NC], ls[NC], gb[NC];
    int tid = threadIdx.x;
    int s = blockIdx.x * S1C;
    int n = NNZ - s; if (n > S1C) n = S1C;
    int r[16];

    if (tid < NC) h[tid] = 0;
    __syncthreads();
    #pragma unroll
    for (int k = 0; k < 16; k++) {         // coalesced load + histogram
        int i = tid + k * 256;
        r[k] = (i < n) ? rows[s + i] : -1;
        if (r[k] >= 0) atomicAdd(&h[r[k] >> 12], 1);
    }
    __syncthreads();
    if (tid == 0) {                        // serial scan over 37 buckets
        int acc = 0;
        for (int i = 0; i < NC; i++) { ls[i] = acc; acc += h[i]; }
    }
    if (tid < NC) gb[tid] = h[tid] ? atomicAdd(&cur1[tid], h[tid]) : 0;
    __syncthreads();
    if (tid < NC) h[tid] = 0;              // reuse as local cursor
    __syncthreads();
    #pragma unroll
    for (int k = 0; k < 16; k++) {         // place into bucket-ordered LDS
        int i = tid + k * 256;
        if (r[k] >= 0) {
            int c = r[k] >> 12;
            int rank = atomicAdd(&h[c], 1);
            int slot = ls[c] + rank;
            int2 p;
            p.x = ((r[k] & 4095) << 18) | cols[s + i];
            p.y = __float_as_int(vals[s + i]);
            buf[slot] = p;
            bk[slot] = (unsigned char)c;
        }
    }
    __syncthreads();
    for (int j = tid; j < n; j += 256) {   // coalesced flush (runs ~110 entries)
        int c = bk[j];
        int o = gb[c] + j - ls[c];
        X[(o < CAPC) ? ((size_t)c * CAPC + o) : ((size_t)NC * CAPC)] = buf[j];
    }
}

// ---------- pass 2: coarse -> 64 fine buckets, LDS sort + coalesced flush ----
// Y pair: x = (col18 << 7) | lr6  (pre-scaled column: x & ~127 = row byte off)
__global__ void __launch_bounds__(256)
lgcn_scatter2(const int2* __restrict__ X,
              const int*  __restrict__ cur1,
              int*        __restrict__ cur2,
              int2*       __restrict__ Y) {
    __shared__ int2 buf[S2C];              // 32 KB
    __shared__ unsigned char bk[S2C];      // 4 KB
    __shared__ int h[NF], ls[NF], gb[NF];
    int c = blockIdx.x / NCH2;
    int ch = blockIdx.x % NCH2;
    int cnt_c = cur1[c]; if (cnt_c > CAPC) cnt_c = CAPC;
    int s = ch * S2C;
    int n = cnt_c - s; if (n > S2C) n = S2C;
    if (n <= 0) return;                    // uniform per block
    int tid = threadIdx.x;
    size_t base = (size_t)c * CAPC + s;
    int2 e[16];

    if (tid < NF) h[tid] = 0;
    __syncthreads();
    #pragma unroll
    for (int k = 0; k < 16; k++) {         // register-stage + histogram
        int i = tid + k * 256;
        if (i < n) {
            e[k] = X[base + i];
            atomicAdd(&h[e[k].x >> 24], 1);   // fine6 = lr12 >> 6
        } else e[k].x = -1;                   // x >= 0 for valid (30-bit)
    }
    __syncthreads();
    if (tid == 0) {
        int acc = 0;
        for (int i = 0; i < NF; i++) { ls[i] = acc; acc += h[i]; }
    }
    if (tid < NF) gb[tid] = h[tid] ? atomicAdd(&cur2[c * NF + tid], h[tid]) : 0;
    __syncthreads();
    if (tid < NF) h[tid] = 0;
    __syncthreads();
    #pragma unroll
    for (int k = 0; k < 16; k++) {
        if (e[k].x >= 0) {
            int f = e[k].x >> 24;
            int rank = atomicAdd(&h[f], 1);
            int slot = ls[f] + rank;
            int2 q;
            q.x = ((e[k].x & 0x3FFFF) << 7) | ((e[k].x >> 18) & 63);  // col<<7|lr6
            q.y = e[k].y;
            buf[slot] = q;
            bk[slot] = (unsigned char)f;
        }
    }
    __syncthreads();
    for (int j = tid; j < n; j += 256) {   // coalesced flush (runs ~64 entries)
        int f = bk[j];
        int o = gb[f] + j - ls[f];
        Y[(o < CAPF) ? ((size_t)(c * NF + f) * CAPF + o)
                     : ((size_t)NBUK * CAPF)] = buf[j];
    }
}

// ---------- init A = bf16(concat(user,item)), 8 elems/thread (G13) ----------
__global__ void lgcn_init_A(const float* __restrict__ user_emb,
                            const float* __restrict__ item_emb,
                            unsigned short* __restrict__ A) {
    int i = blockIdx.x * blockDim.x + threadIdx.x;   // 8-elem group
    if (i < NELEM / 8) {
        const float4* src = (i < (N_USERS * D) / 8)
            ? (const float4*)user_emb + 2 * (size_t)i
            : (const float4*)item_emb + 2 * (size_t)(i - (N_USERS * D) / 8);
        float4 a = src[0], b = src[1];
        uint4 w;
        w.x = (unsigned)f2bf(a.x) | ((unsigned)f2bf(a.y) << 16);
        w.y = (unsigned)f2bf(a.z) | ((unsigned)f2bf(a.w) << 16);
        w.z = (unsigned)f2bf(b.x) | ((unsigned)f2bf(b.y) << 16);
        w.w = (unsigned)f2bf(b.z) | ((unsigned)f2bf(b.w) << 16);
        ((uint4*)A)[i] = w;
    }
}

// ---------- fused: per-bucket row sort + CSR emit + sorted-Y writeback +
//            SpMM layer 1 computed from LDS pairs (wave owns 16 rows) --------
__global__ void __launch_bounds__(256)
lgcn_spmm_sort(int2* __restrict__ Y,
               const int* __restrict__ cur2,
               int* __restrict__ row_ptr,
               int* __restrict__ row_cnt,
               const unsigned short* __restrict__ cur,
               unsigned short* __restrict__ nxt) {
    __shared__ int2 buf[CAPF + 2];     // 25.6 KB -> 6 blocks/CU
    __shared__ int  h[RPB];
    __shared__ int  base[RPB];
    int tid = threadIdx.x;
    int fb = blockIdx.x;
    size_t start = (size_t)fb * CAPF;
    int cnt = cur2[fb]; if (cnt > CAPF) cnt = CAPF;

    // register-stage load + per-row histogram
    int2 e[13];                        // ceil(3200/256) = 13
    if (tid < RPB) h[tid] = 0;
    __syncthreads();
    #pragma unroll
    for (int k = 0; k < 13; k++) {
        int i = tid + k * 256;
        if (i < cnt) {
            e[k] = Y[start + i];
            atomicAdd(&h[e[k].x & 63], 1);
        } else e[k].x = -1;            // valid x >= 0 (25-bit)
    }
    __syncthreads();

    // exclusive scan of h[0..63]
    int v = (tid < RPB) ? h[tid] : 0;
    int sum = v;
    #pragma unroll
    for (int off = 1; off < RPB; off <<= 1) {
        if (tid < RPB) base[tid] = sum;
        __syncthreads();
        if (tid >= off && tid < RPB) sum += base[tid - off];
        __syncthreads();
    }
    if (tid < RPB) {
        int excl = sum - v;
        base[tid] = excl;
        int gr = (fb >> 6) * CROWS + (fb & 63) * RPB + tid;
        if (gr < N_TOTAL) {
            row_ptr[gr] = (int)start + excl;
            row_cnt[gr] = v;
        }
        h[tid] = 0;                    // reuse as per-row cursor
    }
    __syncthreads();

    // place regs -> row-sorted LDS
    #pragma unroll
    for (int k = 0; k < 13; k++) {
        if (e[k].x >= 0) {
            int lr = e[k].x & 63;
            int rank = atomicAdd(&h[lr], 1);
            buf[base[lr] + rank] = e[k];
        }
    }
    __syncthreads();

    // coalesced sorted writeback (layer 2 reads this)
    for (int i = tid; i < cnt; i += 256) Y[start + i] = buf[i];

    // ---- SpMM layer 1 from LDS pairs: wave w owns rows w*16 .. w*16+15 ----
    int wave = tid >> 6, lane = tid & 63;
    int halfid = lane >> 5, hl = lane & 31;
    const char* __restrict__ curb = (const char*)cur + hl * 4;
    for (int lr = wave * 16; lr < wave * 16 + 16; lr++) {
        int rs = base[lr];
        int rc = h[lr];                // == row count after placement
        float sA = 0.f, sB = 0.f;
        int jj = 0;
        for (; jj + 8 <= rc; jj += 8) {            // unguarded dual-edge bodies
            #pragma unroll
            for (int k = 0; k < 4; k++) {
                int2 q = buf[rs + jj + 2 * k + halfid];   // ds_read broadcast
                float v2 = __int_as_float(q.y);
                unsigned off = (unsigned)q.x & 0xFFFFFF80u;
                unsigned u = *(const unsigned*)(curb + off);
                sA = fmaf(v2, __uint_as_float(u << 16), sA);
                sB = fmaf(v2, __uint_as_float(u & 0xFFFF0000u), sB);
            }
        }
        for (; jj < rc; jj += 2) {                 // guarded tail (<=4 iters)
            int2 q = buf[rs + jj + halfid];        // may overread 1 (padded)
            float v2 = __int_as_float(q.y);
            unsigned off = (unsigned)q.x & 0xFFFFFF80u;
            if (jj + halfid >= rc) { v2 = 0.f; off = 0; }
            unsigned u = *(const unsigned*)(curb + off);
            sA = fmaf(v2, __uint_as_float(u << 16), sA);
            sB = fmaf(v2, __uint_as_float(u & 0xFFFF0000u), sB);
        }
        sA += __shfl_xor(sA, 32, 64);
        sB += __shfl_xor(sB, 32, 64);
        int gr = (fb >> 6) * CROWS + (fb & 63) * RPB + lr;
        if (halfid == 0 && gr < N_TOTAL) {
            unsigned int lo = f2bf(sA);
            unsigned int hi = f2bf(sB);
            ((unsigned int*)nxt)[gr * 32 + hl] = lo | (hi << 16);
        }
    }
}

// ---------- SpMM: wave per row, dual-edge, LDS-staged, 16-edge unroll ----------
__global__ void __launch_bounds__(256)
lgcn_spmm_csr(const int2* __restrict__ pairs,
              const int*  __restrict__ row_ptr,
              const int*  __restrict__ row_cnt,
              const unsigned short* __restrict__ cur,
              unsigned short* __restrict__ nxt) {
    __shared__ int2 stage[4][64];
    int t = blockIdx.x * blockDim.x + threadIdx.x;
    int r = t >> 6;
    int lane = t & 63;
    if (r >= N_TOTAL) return;
    int halfid = lane >> 5;
    int hl = lane & 31;
    const char* __restrict__ curb = (const char*)cur + hl * 4;  // lane-folded
    int2* st = stage[threadIdx.x >> 6];
    int start = row_ptr[r];
    int cnt   = row_cnt[r];
    float sA = 0.f, sB = 0.f;
    for (int base = 0; base < cnt; base += 64) {
        int idx = base + lane;
        int2 p = {0, 0};
        if (idx < cnt) p = pairs[start + idx];     // coalesced dwordx2
        st[lane] = p;                              // per-wave slice, no barrier
        int m = cnt - base; if (m > 64) m = 64;
        for (int jj = 0; jj < m; jj += 16) {       // 16 edges per body
            #pragma unroll
            for (int k = 0; k < 8; k++) {
                int2 q = st[jj + 2 * k + halfid];  // ds_read_b64 broadcast
                float v = __int_as_float(q.y);     // 0 beyond cnt
                unsigned off = (unsigned)q.x & 0xFFFFFF80u;   // col*128
                unsigned u = *(const unsigned*)(curb + off);
                sA = fmaf(v, __uint_as_float(u << 16), sA);
                sB = fmaf(v, __uint_as_float(u & 0xFFFF0000u), sB);
            }
        }
    }
    sA += __shfl_xor(sA, 32, 64);
    sB += __shfl_xor(sB, 32, 64);
    if (halfid == 0) {
        unsigned int lo = f2bf(sA);
        unsigned int hi = f2bf(sB);
        ((unsigned int*)nxt)[r * 32 + hl] = lo | (hi << 16);  // half-wave 128B
    }
}

// ---------- layer 3 at sampled rows only: e3[s,:] = (A @ E2)[row(s),:] (f32) ----
__global__ void __launch_bounds__(256)
lgcn_spmm_sampled(const int2* __restrict__ pairs,
                  const int*  __restrict__ row_ptr,
                  const int*  __restrict__ row_cnt,
                  const unsigned short* __restrict__ cur,
                  const int* __restrict__ users,
                  const int* __restrict__ items,
                  float* __restrict__ e3) {
    __shared__ int2 stage[4][64];
    int t = blockIdx.x * blockDim.x + threadIdx.x;
    int s = t >> 6;
    int lane = t & 63;
    if (s >= 2 * BATCH) return;
    int r = (s < BATCH) ? users[s] : (N_USERS + items[s - BATCH]);
    const char* __restrict__ curb = (const char*)cur + lane * 2;  // bf16 dim
    int2* st = stage[threadIdx.x >> 6];
    int start = row_ptr[r];
    int cnt   = row_cnt[r];
    float sum0 = 0.f, sum1 = 0.f;
    for (int base = 0; base < cnt; base += 64) {
        int idx = base + lane;
        int2 p = {0, 0};
        if (idx < cnt) p = pairs[start + idx];
        st[lane] = p;
        int m = cnt - base; if (m > 64) m = 64;
        for (int j = 0; j < m; j += 16) {
            #pragma unroll
            for (int k = 0; k < 16; k++) {
                int2 q = st[j + k];                // broadcast
                float v = __int_as_float(q.y);     // 0 beyond cnt
                unsigned off = (unsigned)q.x & 0xFFFFFF80u;
                unsigned short u = *(const unsigned short*)(curb + off);
                if (k & 1) sum1 = fmaf(v, bf2f(u), sum1);
                else       sum0 = fmaf(v, bf2f(u), sum0);
            }
        }
    }
    e3[s * D + lane] = sum0 + sum1;
}

// ---------- dot: gamma = <E0+E1+E2+E3>_u . <E0+E1+E2+E3>_i / 16 ----------
__global__ void lgcn_dot(const float* __restrict__ user_emb,
                         const float* __restrict__ item_emb,
                         const unsigned short* __restrict__ E1,
                         const unsigned short* __restrict__ E2,
                         const float* __restrict__ e3,
                         const int* __restrict__ users,
                         const int* __restrict__ items,
                         float* __restrict__ out) {
    int t = blockIdx.x * blockDim.x + threadIdx.x;
    int b = t >> 6;
    int d = t & 63;
    if (b < BATCH) {
        int u  = users[b];
        int it = items[b];
        int ur = u * D + d;
        int ir = (N_USERS + it) * D + d;
        float au = user_emb[ur] + bf2f(E1[ur]) + bf2f(E2[ur]) + e3[b * D + d];
        float ai = item_emb[it * D + d] + bf2f(E1[ir]) + bf2f(E2[ir])
                 + e3[(BATCH + b) * D + d];
        float p = au * ai;
        #pragma unroll
        for (int off = 32; off; off >>= 1) p += __shfl_down(p, off, 64);
        if (d == 0) out[b] = p * (1.0f / 16.0f);
    }
}

// ---------- round-1 fallback (atomic scatter) if ws too small ----------
__global__ void lgcn_init_fb(const float* __restrict__ user_emb,
                             const float* __restrict__ item_emb,
                             float* __restrict__ acc,
                             float* __restrict__ cur,
                             float* __restrict__ nxt) {
    int i = blockIdx.x * blockDim.x + threadIdx.x;
    if (i < NELEM) {
        float v = (i < N_USERS * D) ? user_emb[i] : item_emb[i - N_USERS * D];
        acc[i] = v; cur[i] = v; nxt[i] = 0.0f;
    }
}
__global__ void lgcn_spmm_fb(const int* __restrict__ rows,
                             const int* __restrict__ cols,
                             const float* __restrict__ vals,
                             const float* __restrict__ cur,
                             float* __restrict__ nxt) {
    long long t = (long long)blockIdx.x * blockDim.x + threadIdx.x;
    int e = (int)(t >> 6);
    int d = (int)(t & 63);
    if (e < NNZ) {
        float x = cur[cols[e] * D + d];
        unsafeAtomicAdd(&nxt[rows[e] * D + d], vals[e] * x);
    }
}
__global__ void lgcn_accum_fb(float* __restrict__ acc,
                              const float* __restrict__ src,
                              float* __restrict__ to_zero) {
    int i = blockIdx.x * blockDim.x + threadIdx.x;
    if (i < NELEM) {
        acc[i] += src[i];
        if (to_zero) to_zero[i] = 0.0f;
    }
}
__global__ void lgcn_dot_fb(const float* __restrict__ acc,
                            const int* __restrict__ users,
                            const int* __restrict__ items,
                            float* __restrict__ out) {
    int t = blockIdx.x * blockDim.x + threadIdx.x;
    int b = t >> 6;
    int d = t & 63;
    if (b < BATCH) {
        int u  = users[b];
        int it = items[b];
        float p = acc[u * D + d] * acc[(N_USERS + it) * D + d];
        #pragma unroll
        for (int off = 32; off; off >>= 1) p += __shfl_down(p, off, 64);
        if (d == 0) out[b] = p * (1.0f / 16.0f);
    }
}

extern "C" void kernel_launch(void* const* d_in, const int* in_sizes, int n_in,
                              void* d_out, int out_size, void* d_ws, size_t ws_size,
                              hipStream_t stream) {
    const float* user_emb = (const float*)d_in[0];
    const float* item_emb = (const float*)d_in[1];
    const int*   edge_row = (const int*)d_in[2];
    const int*   edge_col = (const int*)d_in[3];
    const float* edge_val = (const float*)d_in[4];
    const int*   users    = (const int*)d_in[5];
    const int*   items    = (const int*)d_in[6];
    float*       out      = (float*)d_out;

    const int TPB = 256;
    int init_blocks  = (NELEM + TPB - 1) / TPB;
    int init8_blocks = (NELEM / 8 + TPB - 1) / TPB;
    int spmm_blocks = (N_TOTAL * 64 + TPB - 1) / TPB;       // wave per row
    int samp_blocks = (2 * BATCH * 64 + TPB - 1) / TPB;     // wave per sampled row
    int dot_blocks  = (BATCH * 64 + TPB - 1) / TPB;

    // workspace layout (~121.5MB, proven family):
    //   X (coarse pairs, +1 sink) — dead after pass 2; A,B,C bf16 ALL alias it
    //     (CAPC sized so X bytes >= 3*NELEM*2 = 57.6MB)
    //   Y (fine pairs, +1 sink)   — row-sorted in the fused kernel
    //   e3 f32, cursors, row_ptr/row_cnt
    int2* X = (int2*)d_ws;                              // NC*CAPC + 1
    int2* Y = X + (size_t)NC * CAPC + 1;                // NBUK*CAPF + 1
    float* e3 = (float*)(Y + (size_t)NBUK * CAPF + 1);  // 2*BATCH*D
    int* cur1 = (int*)(e3 + 2 * BATCH * D);             // NC
    int* cur2 = cur1 + NC;                              // NBUK
    int* row_ptr = cur2 + NBUK;                         // NBUK*RPB
    int* row_cnt = row_ptr + NBUK * RPB;                // NBUK*RPB
    size_t req = (size_t)((char*)(row_cnt + NBUK * RPB) - (char*)d_ws);
    unsigned short* A = (unsigned short*)X;             // alias: init after pass 2
    unsigned short* B = A + NELEM;                      // alias
    unsigned short* C = B + NELEM;                      // alias: 57.6MB <= X bytes

    if (ws_size < req && ws_size >= (size_t)3 * NELEM * 4) {
        // fallback: round-1 atomic path (needs only 3*NELEM floats)
        float* acc = (float*)d_ws;
        float* Af  = acc + NELEM;
        float* Bf  = Af + NELEM;
        long long st = (long long)NNZ * 64;
        int sb = (int)((st + TPB - 1) / TPB);
        lgcn_init_fb<<<init_blocks, TPB, 0, stream>>>(user_emb, item_emb, acc, Af, Bf);
        lgcn_spmm_fb<<<sb, TPB, 0, stream>>>(edge_row, edge_col, edge_val, Af, Bf);
        lgcn_accum_fb<<<init_blocks, TPB, 0, stream>>>(acc, Bf, Af);
        lgcn_spmm_fb<<<sb, TPB, 0, stream>>>(edge_row, edge_col, edge_val, Bf, Af);
        lgcn_accum_fb<<<init_blocks, TPB, 0, stream>>>(acc, Af, Bf);
        lgcn_spmm_fb<<<sb, TPB, 0, stream>>>(edge_row, edge_col, edge_val, Af, Bf);
        lgcn_accum_fb<<<init_blocks, TPB, 0, stream>>>(acc, Bf, nullptr);
        lgcn_dot_fb<<<dot_blocks, TPB, 0, stream>>>(acc, users, items, out);
        return;
    }

    // two-level radix binning (LDS-sorted, coalesced flush)
    lgcn_zero<<<1, TPB, 0, stream>>>(cur1, cur2);
    lgcn_scatter1<<<S1EB, TPB, 0, stream>>>(edge_row, edge_col, edge_val, cur1, X);
    lgcn_scatter2<<<NC * NCH2, TPB, 0, stream>>>(X, cur1, cur2, Y);

    // E0 bf16 (A aliases dead X region)
    lgcn_init_A<<<init8_blocks, TPB, 0, stream>>>(user_emb, item_emb, A);

    // fused: row sort + CSR emit + sorted-Y writeback + layer 1 from LDS
    lgcn_spmm_sort<<<NBUK, TPB, 0, stream>>>(Y, cur2, row_ptr, row_cnt, A, B);

    // layer 2 full width (bf16); layer 3 only at sampled rows (f32)
    lgcn_spmm_csr<<<spmm_blocks, TPB, 0, stream>>>(Y, row_ptr, row_cnt, B, C);
    lgcn_spmm_sampled<<<samp_blocks, TPB, 0, stream>>>(Y, row_ptr, row_cnt, C,
                                                       users, items, e3);

    // gamma
    lgcn_dot<<<dot_blocks, TPB, 0, stream>>>(user_emb, item_emb, B, C, e3,
                                             users, items, out);
}

// Round 12
// 455.682 us; speedup vs baseline: 1.1056x; 1.0104x over previous
//
#include <hip/hip_runtime.h>
#include <hip/hip_bf16.h>

// LightGCN forward on MI355X — round 21.
// r20 post-mortem: occupancy-cap lift (5->6 blocks/CU) left spmm_sort at
//   ~124us, occ 47-49% — both spmm kernels confirmed at the ~3.5TB/s
//   beyond-L2 random-gather wall (L3 ceiling). Layers 1+2 ~= 224us floor.
//   Budget: ~200us sits in scatter1+scatter2 vs ~40us streaming roofline.
// r21: single-atomic-pass ranks — the histogram atomicAdd's return value IS
//   the within-bucket rank (edge order in a bucket is already nondet; CSR
//   order-agnostic). Merging rank capture into the histogram pass halves
//   LDS-atomic rounds and drops a barrier+reset in scatter1, scatter2, AND
//   spmm_sort's row sort (h survives as row counts for free).

#define N_USERS  100000
#define N_ITEMS  50000
#define N_TOTAL  150000          // N_USERS + N_ITEMS
#define D        64
#define NNZ      6400000
#define BATCH    4096
#define NELEM    (N_TOTAL * D)   // 9,600,000

#define NC       37              // coarse buckets (4096 rows each)
#define CROWS    4096
#define CAPC     194600          // coarse capacity (mean 174763 + 48 sigma);
                                 // also sized so X >= A+B+C (57.6MB aliasing)
#define S1C      4096            // scatter1 chunk (fits 32KB LDS stage)
#define S1EB     ((NNZ + S1C - 1) / S1C)       // 1563
#define S2C      4096
#define NCH2     ((CAPC + S2C - 1) / S2C)      // 48 chunks per coarse region
#define NF       64              // fine buckets per coarse (64 rows each)
#define RPB      64
#define NBUK     (NC * NF)       // 2368 fine buckets
#define CAPF     3200            // fine capacity = mean 2731 + 9 sigma
                                 // (est. true max ~2937 for the fixed seed)

__device__ __forceinline__ float bf2f(unsigned short h) {
    return __uint_as_float(((unsigned int)h) << 16);
}
__device__ __forceinline__ unsigned short f2bf(float f) {
    __hip_bfloat16 b = __float2bfloat16(f);   // RNE
    return *(unsigned short*)&b;
}

// ---------- zero cursors ----------
__global__ void lgcn_zero(int* __restrict__ cur1, int* __restrict__ cur2) {
    int i = threadIdx.x;
    if (i < NC) cur1[i] = 0;
    for (int j = i; j < NBUK; j += 256) cur2[j] = 0;
}

// ---------- pass 1: COO -> 37 coarse buckets, LDS sort + coalesced flush ----
// X pair: x = (row_in_coarse<<18) | col  (12b + 18b), y = val bits
// Single atomic pass: histogram atomicAdd return value = within-bucket rank.
__global__ void __launch_bounds__(256)
lgcn_scatter1(const int*   __restrict__ rows,
              const int*   __restrict__ cols,
              const float* __restrict__ vals,
              int*         __restrict__ cur1,
              int2*        __restrict__ X) {
    __shared__ int2 buf[S1C];              // 32 KB
    __shared__ unsigned char bk[S1C];      // 4 KB (bucket of slot)
    __shared__ int h[NC], ls[NC], gb[NC];
    int tid = threadIdx.x;
    int s = blockIdx.x * S1C;
    int n = NNZ - s; if (n > S1C) n = S1C;
    int r[16], rk[16];

    if (tid < NC) h[tid] = 0;
    __syncthreads();
    #pragma unroll
    for (int k = 0; k < 16; k++) {         // load + histogram + rank (merged)
        int i = tid + k * 256;
        r[k] = (i < n) ? rows[s + i] : -1;
        if (r[k] >= 0) rk[k] = atomicAdd(&h[r[k] >> 12], 1);
    }
    __syncthreads();
    if (tid == 0) {                        // serial scan over 37 buckets
        int acc = 0;
        for (int i = 0; i < NC; i++) { ls[i] = acc; acc += h[i]; }
    }
    if (tid < NC) gb[tid] = h[tid] ? atomicAdd(&cur1[tid], h[tid]) : 0;
    __syncthreads();
    #pragma unroll
    for (int k = 0; k < 16; k++) {         // placement: NO atomics
        int i = tid + k * 256;
        if (r[k] >= 0) {
            int c = r[k] >> 12;
            int slot = ls[c] + rk[k];
            int2 p;
            p.x = ((r[k] & 4095) << 18) | cols[s + i];   // L2-hot reload
            p.y = __float_as_int(vals[s + i]);
            buf[slot] = p;
            bk[slot] = (unsigned char)c;
        }
    }
    __syncthreads();
    for (int j = tid; j < n; j += 256) {   // coalesced flush (runs ~110 entries)
        int c = bk[j];
        int o = gb[c] + j - ls[c];
        X[(o < CAPC) ? ((size_t)c * CAPC + o) : ((size_t)NC * CAPC)] = buf[j];
    }
}

// ---------- pass 2: coarse -> 64 fine buckets, LDS sort + coalesced flush ----
// Y pair: x = (col18 << 7) | lr6  (pre-scaled column: x & ~127 = row byte off)
__global__ void __launch_bounds__(256)
lgcn_scatter2(const int2* __restrict__ X,
              const int*  __restrict__ cur1,
              int*        __restrict__ cur2,
              int2*       __restrict__ Y) {
    __shared__ int2 buf[S2C];              // 32 KB
    __shared__ unsigned char bk[S2C];      // 4 KB
    __shared__ int h[NF], ls[NF], gb[NF];
    int c = blockIdx.x / NCH2;
    int ch = blockIdx.x % NCH2;
    int cnt_c = cur1[c]; if (cnt_c > CAPC) cnt_c = CAPC;
    int s = ch * S2C;
    int n = cnt_c - s; if (n > S2C) n = S2C;
    if (n <= 0) return;                    // uniform per block
    int tid = threadIdx.x;
    size_t base = (size_t)c * CAPC + s;
    int2 e[16];
    int rk[16];

    if (tid < NF) h[tid] = 0;
    __syncthreads();
    #pragma unroll
    for (int k = 0; k < 16; k++) {         // stage + histogram + rank (merged)
        int i = tid + k * 256;
        if (i < n) {
            e[k] = X[base + i];
            rk[k] = atomicAdd(&h[e[k].x >> 24], 1);   // fine6 = lr12 >> 6
        } else e[k].x = -1;                           // x >= 0 for valid
    }
    __syncthreads();
    if (tid == 0) {
        int acc = 0;
        for (int i = 0; i < NF; i++) { ls[i] = acc; acc += h[i]; }
    }
    if (tid < NF) gb[tid] = h[tid] ? atomicAdd(&cur2[c * NF + tid], h[tid]) : 0;
    __syncthreads();
    #pragma unroll
    for (int k = 0; k < 16; k++) {         // placement: NO atomics
        if (e[k].x >= 0) {
            int f = e[k].x >> 24;
            int slot = ls[f] + rk[k];
            int2 q;
            q.x = ((e[k].x & 0x3FFFF) << 7) | ((e[k].x >> 18) & 63);  // col<<7|lr6
            q.y = e[k].y;
            buf[slot] = q;
            bk[slot] = (unsigned char)f;
        }
    }
    __syncthreads();
    for (int j = tid; j < n; j += 256) {   // coalesced flush (runs ~64 entries)
        int f = bk[j];
        int o = gb[f] + j - ls[f];
        Y[(o < CAPF) ? ((size_t)(c * NF + f) * CAPF + o)
                     : ((size_t)NBUK * CAPF)] = buf[j];
    }
}

// ---------- init A = bf16(concat(user,item)), 8 elems/thread (G13) ----------
__global__ void lgcn_init_A(const float* __restrict__ user_emb,
                            const float* __restrict__ item_emb,
                            unsigned short* __restrict__ A) {
    int i = blockIdx.x * blockDim.x + threadIdx.x;   // 8-elem group
    if (i < NELEM / 8) {
        const float4* src = (i < (N_USERS * D) / 8)
            ? (const float4*)user_emb + 2 * (size_t)i
            : (const float4*)item_emb + 2 * (size_t)(i - (N_USERS * D) / 8);
        float4 a = src[0], b = src[1];
        uint4 w;
        w.x = (unsigned)f2bf(a.x) | ((unsigned)f2bf(a.y) << 16);
        w.y = (unsigned)f2bf(a.z) | ((unsigned)f2bf(a.w) << 16);
        w.z = (unsigned)f2bf(b.x) | ((unsigned)f2bf(b.y) << 16);
        w.w = (unsigned)f2bf(b.z) | ((unsigned)f2bf(b.w) << 16);
        ((uint4*)A)[i] = w;
    }
}

// ---------- fused: per-bucket row sort + CSR emit + sorted-Y writeback +
//            SpMM layer 1 computed from LDS pairs (wave owns 16 rows) --------
__global__ void __launch_bounds__(256)
lgcn_spmm_sort(int2* __restrict__ Y,
               const int* __restrict__ cur2,
               int* __restrict__ row_ptr,
               int* __restrict__ row_cnt,
               const unsigned short* __restrict__ cur,
               unsigned short* __restrict__ nxt) {
    __shared__ int2 buf[CAPF + 2];     // 25.6 KB -> 6 blocks/CU
    __shared__ int  h[RPB];
    __shared__ int  base[RPB];
    int tid = threadIdx.x;
    int fb = blockIdx.x;
    size_t start = (size_t)fb * CAPF;
    int cnt = cur2[fb]; if (cnt > CAPF) cnt = CAPF;

    // register-stage load + per-row histogram + rank (merged, single pass)
    int2 e[13];                        // ceil(3200/256) = 13
    int rk[13];
    if (tid < RPB) h[tid] = 0;
    __syncthreads();
    #pragma unroll
    for (int k = 0; k < 13; k++) {
        int i = tid + k * 256;
        if (i < cnt) {
            e[k] = Y[start + i];
            rk[k] = atomicAdd(&h[e[k].x & 63], 1);
        } else e[k].x = -1;            // valid x >= 0 (25-bit)
    }
    __syncthreads();

    // exclusive scan of h[0..63]
    int v = (tid < RPB) ? h[tid] : 0;
    int sum = v;
    #pragma unroll
    for (int off = 1; off < RPB; off <<= 1) {
        if (tid < RPB) base[tid] = sum;
        __syncthreads();
        if (tid >= off && tid < RPB) sum += base[tid - off];
        __syncthreads();
    }
    if (tid < RPB) {
        int excl = sum - v;
        base[tid] = excl;
        int gr = (fb >> 6) * CROWS + (fb & 63) * RPB + tid;
        if (gr < N_TOTAL) {
            row_ptr[gr] = (int)start + excl;
            row_cnt[gr] = v;
        }
        // h NOT reset: h[lr] survives as row count for the compute phase
    }
    __syncthreads();

    // place regs -> row-sorted LDS (no atomics)
    #pragma unroll
    for (int k = 0; k < 13; k++) {
        if (e[k].x >= 0) {
            int lr = e[k].x & 63;
            buf[base[lr] + rk[k]] = e[k];
        }
    }
    __syncthreads();

    // coalesced sorted writeback (layer 2 reads this)
    for (int i = tid; i < cnt; i += 256) Y[start + i] = buf[i];

    // ---- SpMM layer 1 from LDS pairs: wave w owns rows w*16 .. w*16+15 ----
    int wave = tid >> 6, lane = tid & 63;
    int halfid = lane >> 5, hl = lane & 31;
    const char* __restrict__ curb = (const char*)cur + hl * 4;
    for (int lr = wave * 16; lr < wave * 16 + 16; lr++) {
        int rs = base[lr];
        int rc = h[lr];                // row count (preserved)
        float sA = 0.f, sB = 0.f;
        int jj = 0;
        for (; jj + 8 <= rc; jj += 8) {            // unguarded dual-edge bodies
            #pragma unroll
            for (int k = 0; k < 4; k++) {
                int2 q = buf[rs + jj + 2 * k + halfid];   // ds_read broadcast
                float v2 = __int_as_float(q.y);
                unsigned off = (unsigned)q.x & 0xFFFFFF80u;
                unsigned u = *(const unsigned*)(curb + off);
                sA = fmaf(v2, __uint_as_float(u << 16), sA);
                sB = fmaf(v2, __uint_as_float(u & 0xFFFF0000u), sB);
            }
        }
        for (; jj < rc; jj += 2) {                 // guarded tail (<=4 iters)
            int2 q = buf[rs + jj + halfid];        // may overread 1 (padded)
            float v2 = __int_as_float(q.y);
            unsigned off = (unsigned)q.x & 0xFFFFFF80u;
            if (jj + halfid >= rc) { v2 = 0.f; off = 0; }
            unsigned u = *(const unsigned*)(curb + off);
            sA = fmaf(v2, __uint_as_float(u << 16), sA);
            sB = fmaf(v2, __uint_as_float(u & 0xFFFF0000u), sB);
        }
        sA += __shfl_xor(sA, 32, 64);
        sB += __shfl_xor(sB, 32, 64);
        int gr = (fb >> 6) * CROWS + (fb & 63) * RPB + lr;
        if (halfid == 0 && gr < N_TOTAL) {
            unsigned int lo = f2bf(sA);
            unsigned int hi = f2bf(sB);
            ((unsigned int*)nxt)[gr * 32 + hl] = lo | (hi << 16);
        }
    }
}

// ---------- SpMM: wave per row, dual-edge, LDS-staged, 16-edge unroll ----------
__global__ void __launch_bounds__(256)
lgcn_spmm_csr(const int2* __restrict__ pairs,
              const int*  __restrict__ row_ptr,
              const int*  __restrict__ row_cnt,
              const unsigned short* __restrict__ cur,
              unsigned short* __restrict__ nxt) {
    __shared__ int2 stage[4][64];
    int t = blockIdx.x * blockDim.x + threadIdx.x;
    int r = t >> 6;
    int lane = t & 63;
    if (r >= N_TOTAL) return;
    int halfid = lane >> 5;
    int hl = lane & 31;
    const char* __restrict__ curb = (const char*)cur + hl * 4;  // lane-folded
    int2* st = stage[threadIdx.x >> 6];
    int start = row_ptr[r];
    int cnt   = row_cnt[r];
    float sA = 0.f, sB = 0.f;
    for (int base = 0; base < cnt; base += 64) {
        int idx = base + lane;
        int2 p = {0, 0};
        if (idx < cnt) p = pairs[start + idx];     // coalesced dwordx2
        st[lane] = p;                              // per-wave slice, no barrier
        int m = cnt - base; if (m > 64) m = 64;
        for (int jj = 0; jj < m; jj += 16) {       // 16 edges per body
            #pragma unroll
            for (int k = 0; k < 8; k++) {
                int2 q = st[jj + 2 * k + halfid];  // ds_read_b64 broadcast
                float v = __int_as_float(q.y);     // 0 beyond cnt
                unsigned off = (unsigned)q.x & 0xFFFFFF80u;   // col*128
                unsigned u = *(const unsigned*)(curb + off);
                sA = fmaf(v, __uint_as_float(u << 16), sA);
                sB = fmaf(v, __uint_as_float(u & 0xFFFF0000u), sB);
            }
        }
    }
    sA += __shfl_xor(sA, 32, 64);
    sB += __shfl_xor(sB, 32, 64);
    if (halfid == 0) {
        unsigned int lo = f2bf(sA);
        unsigned int hi = f2bf(sB);
        ((unsigned int*)nxt)[r * 32 + hl] = lo | (hi << 16);  // half-wave 128B
    }
}

// ---------- layer 3 at sampled rows only: e3[s,:] = (A @ E2)[row(s),:] (f32) ----
__global__ void __launch_bounds__(256)
lgcn_spmm_sampled(const int2* __restrict__ pairs,
                  const int*  __restrict__ row_ptr,
                  const int*  __restrict__ row_cnt,
                  const unsigned short* __restrict__ cur,
                  const int* __restrict__ users,
                  const int* __restrict__ items,
                  float* __restrict__ e3) {
    __shared__ int2 stage[4][64];
    int t = blockIdx.x * blockDim.x + threadIdx.x;
    int s = t >> 6;
    int lane = t & 63;
    if (s >= 2 * BATCH) return;
    int r = (s < BATCH) ? users[s] : (N_USERS + items[s - BATCH]);
    const char* __restrict__ curb = (const char*)cur + lane * 2;  // bf16 dim
    int2* st = stage[threadIdx.x >> 6];
    int start = row_ptr[r];
    int cnt   = row_cnt[r];
    float sum0 = 0.f, sum1 = 0.f;
    for (int base = 0; base < cnt; base += 64) {
        int idx = base + lane;
        int2 p = {0, 0};
        if (idx < cnt) p = pairs[start + idx];
        st[lane] = p;
        int m = cnt - base; if (m > 64) m = 64;
        for (int j = 0; j < m; j += 16) {
            #pragma unroll
            for (int k = 0; k < 16; k++) {
                int2 q = st[j + k];                // broadcast
                float v = __int_as_float(q.y);     // 0 beyond cnt
                unsigned off = (unsigned)q.x & 0xFFFFFF80u;
                unsigned short u = *(const unsigned short*)(curb + off);
                if (k & 1) sum1 = fmaf(v, bf2f(u), sum1);
                else       sum0 = fmaf(v, bf2f(u), sum0);
            }
        }
    }
    e3[s * D + lane] = sum0 + sum1;
}

// ---------- dot: gamma = <E0+E1+E2+E3>_u . <E0+E1+E2+E3>_i / 16 ----------
__global__ void lgcn_dot(const float* __restrict__ user_emb,
                         const float* __restrict__ item_emb,
                         const unsigned short* __restrict__ E1,
                         const unsigned short* __restrict__ E2,
                         const float* __restrict__ e3,
                         const int* __restrict__ users,
                         const int* __restrict__ items,
                         float* __restrict__ out) {
    int t = blockIdx.x * blockDim.x + threadIdx.x;
    int b = t >> 6;
    int d = t & 63;
    if (b < BATCH) {
        int u  = users[b];
        int it = items[b];
        int ur = u * D + d;
        int ir = (N_USERS + it) * D + d;
        float au = user_emb[ur] + bf2f(E1[ur]) + bf2f(E2[ur]) + e3[b * D + d];
        float ai = item_emb[it * D + d] + bf2f(E1[ir]) + bf2f(E2[ir])
                 + e3[(BATCH + b) * D + d];
        float p = au * ai;
        #pragma unroll
        for (int off = 32; off; off >>= 1) p += __shfl_down(p, off, 64);
        if (d == 0) out[b] = p * (1.0f / 16.0f);
    }
}

// ---------- round-1 fallback (atomic scatter) if ws too small ----------
__global__ void lgcn_init_fb(const float* __restrict__ user_emb,
                             const float* __restrict__ item_emb,
                             float* __restrict__ acc,
                             float* __restrict__ cur,
                             float* __restrict__ nxt) {
    int i = blockIdx.x * blockDim.x + threadIdx.x;
    if (i < NELEM) {
        float v = (i < N_USERS * D) ? user_emb[i] : item_emb[i - N_USERS * D];
        acc[i] = v; cur[i] = v; nxt[i] = 0.0f;
    }
}
__global__ void lgcn_spmm_fb(const int* __restrict__ rows,
                             const int* __restrict__ cols,
                             const float* __restrict__ vals,
                             const float* __restrict__ cur,
                             float* __restrict__ nxt) {
    long long t = (long long)blockIdx.x * blockDim.x + threadIdx.x;
    int e = (int)(t >> 6);
    int d = (int)(t & 63);
    if (e < NNZ) {
        float x = cur[cols[e] * D + d];
        unsafeAtomicAdd(&nxt[rows[e] * D + d], vals[e] * x);
    }
}
__global__ void lgcn_accum_fb(float* __restrict__ acc,
                              const float* __restrict__ src,
                              float* __restrict__ to_zero) {
    int i = blockIdx.x * blockDim.x + threadIdx.x;
    if (i < NELEM) {
        acc[i] += src[i];
        if (to_zero) to_zero[i] = 0.0f;
    }
}
__global__ void lgcn_dot_fb(const float* __restrict__ acc,
                            const int* __restrict__ users,
                            const int* __restrict__ items,
                            float* __restrict__ out) {
    int t = blockIdx.x * blockDim.x + threadIdx.x;
    int b = t >> 6;
    int d = t & 63;
    if (b < BATCH) {
        int u  = users[b];
        int it = items[b];
        float p = acc[u * D + d] * acc[(N_USERS + it) * D + d];
        #pragma unroll
        for (int off = 32; off; off >>= 1) p += __shfl_down(p, off, 64);
        if (d == 0) out[b] = p * (1.0f / 16.0f);
    }
}

extern "C" void kernel_launch(void* const* d_in, const int* in_sizes, int n_in,
                              void* d_out, int out_size, void* d_ws, size_t ws_size,
                              hipStream_t stream) {
    const float* user_emb = (const float*)d_in[0];
    const float* item_emb = (const float*)d_in[1];
    const int*   edge_row = (const int*)d_in[2];
    const int*   edge_col = (const int*)d_in[3];
    const float* edge_val = (const float*)d_in[4];
    const int*   users    = (const int*)d_in[5];
    const int*   items    = (const int*)d_in[6];
    float*       out      = (float*)d_out;

    const int TPB = 256;
    int init_blocks  = (NELEM + TPB - 1) / TPB;
    int init8_blocks = (NELEM / 8 + TPB - 1) / TPB;
    int spmm_blocks = (N_TOTAL * 64 + TPB - 1) / TPB;       // wave per row
    int samp_blocks = (2 * BATCH * 64 + TPB - 1) / TPB;     // wave per sampled row
    int dot_blocks  = (BATCH * 64 + TPB - 1) / TPB;

    // workspace layout (~121.5MB, proven family):
    //   X (coarse pairs, +1 sink) — dead after pass 2; A,B,C bf16 ALL alias it
    //     (CAPC sized so X bytes >= 3*NELEM*2 = 57.6MB)
    //   Y (fine pairs, +1 sink)   — row-sorted in the fused kernel
    //   e3 f32, cursors, row_ptr/row_cnt
    int2* X = (int2*)d_ws;                              // NC*CAPC + 1
    int2* Y = X + (size_t)NC * CAPC + 1;                // NBUK*CAPF + 1
    float* e3 = (float*)(Y + (size_t)NBUK * CAPF + 1);  // 2*BATCH*D
    int* cur1 = (int*)(e3 + 2 * BATCH * D);             // NC
    int* cur2 = cur1 + NC;                              // NBUK
    int* row_ptr = cur2 + NBUK;                         // NBUK*RPB
    int* row_cnt = row_ptr + NBUK * RPB;                // NBUK*RPB
    size_t req = (size_t)((char*)(row_cnt + NBUK * RPB) - (char*)d_ws);
    unsigned short* A = (unsigned short*)X;             // alias: init after pass 2
    unsigned short* B = A + NELEM;                      // alias
    unsigned short* C = B + NELEM;                      // alias: 57.6MB <= X bytes

    if (ws_size < req && ws_size >= (size_t)3 * NELEM * 4) {
        // fallback: round-1 atomic path (needs only 3*NELEM floats)
        float* acc = (float*)d_ws;
        float* Af  = acc + NELEM;
        float* Bf  = Af + NELEM;
        long long st = (long long)NNZ * 64;
        int sb = (int)((st + TPB - 1) / TPB);
        lgcn_init_fb<<<init_blocks, TPB, 0, stream>>>(user_emb, item_emb, acc, Af, Bf);
        lgcn_spmm_fb<<<sb, TPB, 0, stream>>>(edge_row, edge_col, edge_val, Af, Bf);
        lgcn_accum_fb<<<init_blocks, TPB, 0, stream>>>(acc, Bf, Af);
        lgcn_spmm_fb<<<sb, TPB, 0, stream>>>(edge_row, edge_col, edge_val, Bf, Af);
        lgcn_accum_fb<<<init_blocks, TPB, 0, stream>>>(acc, Af, Bf);
        lgcn_spmm_fb<<<sb, TPB, 0, stream>>>(edge_row, edge_col, edge_val, Af, Bf);
        lgcn_accum_fb<<<init_blocks, TPB, 0, stream>>>(acc, Bf, nullptr);
        lgcn_dot_fb<<<dot_blocks, TPB, 0, stream>>>(acc, users, items, out);
        return;
    }

    // two-level radix binning (LDS-sorted, coalesced flush, single atomic pass)
    lgcn_zero<<<1, TPB, 0, stream>>>(cur1, cur2);
    lgcn_scatter1<<<S1EB, TPB, 0, stream>>>(edge_row, edge_col, edge_val, cur1, X);
    lgcn_scatter2<<<NC * NCH2, TPB, 0, stream>>>(X, cur1, cur2, Y);

    // E0 bf16 (A aliases dead X region)
    lgcn_init_A<<<init8_blocks, TPB, 0, stream>>>(user_emb, item_emb, A);

    // fused: row sort + CSR emit + sorted-Y writeback + layer 1 from LDS
    lgcn_spmm_sort<<<NBUK, TPB, 0, stream>>>(Y, cur2, row_ptr, row_cnt, A, B);

    // layer 2 full width (bf16); layer 3 only at sampled rows (f32)
    lgcn_spmm_csr<<<spmm_blocks, TPB, 0, stream>>>(Y, row_ptr, row_cnt, B, C);
    lgcn_spmm_sampled<<<samp_blocks, TPB, 0, stream>>>(Y, row_ptr, row_cnt, C,
                                                       users, items, e3);

    // gamma
    lgcn_dot<<<dot_blocks, TPB, 0, stream>>>(user_emb, item_emb, B, C, e3,
                                             users, items, out);
}

// Round 13
// 447.485 us; speedup vs baseline: 1.1259x; 1.0183x over previous
//
#include <hip/hip_runtime.h>
#include <hip/hip_bf16.h>

// LightGCN forward on MI355X — round 22.
// r21 post-mortem: single-atomic-pass moved only ~3us — scatters NOT
//   LDS-atomic-bound. Budget: scatter1+scatter2 ~190us vs ~30us streaming
//   roofline; counting-sort scatters never occupancy-probed (36.8KB LDS ->
//   4 blocks/CU = 50% occ, 3 barrier-separated phases stall all waves).
// r22 (scatters only; spmm kernels byte-identical at their proven walls):
//   (a) chunk 4096->3328: LDS 29.7KB -> 5 blocks/CU (20 waves, 62%);
//   (b) scatter1 keeps cols/vals in regs (kills 51MB partially-evicted
//       reload; +26 VGPR, ~70 total);
//   (c) cur1 padded to one cache line per counter (1924 blocks x 37
//       barrier-blocking atomics serialized on 2 lines otherwise).

#define N_USERS  100000
#define N_ITEMS  50000
#define N_TOTAL  150000          // N_USERS + N_ITEMS
#define D        64
#define NNZ      6400000
#define BATCH    4096
#define NELEM    (N_TOTAL * D)   // 9,600,000

#define NC       37              // coarse buckets (4096 rows each)
#define CROWS    4096
#define CAPC     194600          // coarse capacity (mean 174763 + 48 sigma);
                                 // also sized so X >= A+B+C (57.6MB aliasing)
#define S1C      3328            // scatter chunk (13 per thread; 29.7KB LDS)
#define S1EB     ((NNZ + S1C - 1) / S1C)       // 1924
#define S2C      3328
#define NCH2     ((CAPC + S2C - 1) / S2C)      // 59 chunks per coarse region
#define NF       64              // fine buckets per coarse (64 rows each)
#define RPB      64
#define NBUK     (NC * NF)       // 2368 fine buckets
#define CAPF     3200            // fine capacity = mean 2731 + 9 sigma
#define CPAD     16              // cur1 padding: one 64B line per counter

__device__ __forceinline__ float bf2f(unsigned short h) {
    return __uint_as_float(((unsigned int)h) << 16);
}
__device__ __forceinline__ unsigned short f2bf(float f) {
    __hip_bfloat16 b = __float2bfloat16(f);   // RNE
    return *(unsigned short*)&b;
}

// ---------- zero cursors ----------
__global__ void lgcn_zero(int* __restrict__ cur1, int* __restrict__ cur2) {
    int i = threadIdx.x;
    for (int j = i; j < NC * CPAD; j += 256) cur1[j] = 0;
    for (int j = i; j < NBUK; j += 256) cur2[j] = 0;
}

// ---------- pass 1: COO -> 37 coarse buckets, LDS sort + coalesced flush ----
// X pair: x = (row_in_coarse<<18) | col  (12b + 18b), y = val bits
// Single atomic pass: histogram atomicAdd return value = within-bucket rank.
__global__ void __launch_bounds__(256)
lgcn_scatter1(const int*   __restrict__ rows,
              const int*   __restrict__ cols,
              const float* __restrict__ vals,
              int*         __restrict__ cur1,
              int2*        __restrict__ X) {
    __shared__ int2 buf[S1C];              // 26 KB
    __shared__ unsigned char bk[S1C];      // 3.25 KB (bucket of slot)
    __shared__ int h[NC], ls[NC], gb[NC];
    int tid = threadIdx.x;
    int s = blockIdx.x * S1C;
    int n = NNZ - s; if (n > S1C) n = S1C;
    int r[13], rk[13], c16[13], v16[13];

    if (tid < NC) h[tid] = 0;
    __syncthreads();
    #pragma unroll
    for (int k = 0; k < 13; k++) {         // load all 3 streams + hist + rank
        int i = tid + k * 256;
        if (i < n) {
            r[k]   = rows[s + i];
            c16[k] = cols[s + i];
            v16[k] = __float_as_int(vals[s + i]);
            rk[k]  = atomicAdd(&h[r[k] >> 12], 1);
        } else r[k] = -1;
    }
    __syncthreads();
    if (tid == 0) {                        // serial scan over 37 buckets
        int acc = 0;
        for (int i = 0; i < NC; i++) { ls[i] = acc; acc += h[i]; }
    }
    if (tid < NC) gb[tid] = h[tid] ? atomicAdd(&cur1[tid * CPAD], h[tid]) : 0;
    __syncthreads();
    #pragma unroll
    for (int k = 0; k < 13; k++) {         // placement: regs only, NO atomics
        if (r[k] >= 0) {
            int c = r[k] >> 12;
            int slot = ls[c] + rk[k];
            int2 p;
            p.x = ((r[k] & 4095) << 18) | c16[k];
            p.y = v16[k];
            buf[slot] = p;
            bk[slot] = (unsigned char)c;
        }
    }
    __syncthreads();
    for (int j = tid; j < n; j += 256) {   // coalesced flush (runs ~90 entries)
        int c = bk[j];
        int o = gb[c] + j - ls[c];
        X[(o < CAPC) ? ((size_t)c * CAPC + o) : ((size_t)NC * CAPC)] = buf[j];
    }
}

// ---------- pass 2: coarse -> 64 fine buckets, LDS sort + coalesced flush ----
// Y pair: x = (col18 << 7) | lr6  (pre-scaled column: x & ~127 = row byte off)
__global__ void __launch_bounds__(256)
lgcn_scatter2(const int2* __restrict__ X,
              const int*  __restrict__ cur1,
              int*        __restrict__ cur2,
              int2*       __restrict__ Y) {
    __shared__ int2 buf[S2C];              // 26 KB
    __shared__ unsigned char bk[S2C];      // 3.25 KB
    __shared__ int h[NF], ls[NF], gb[NF];
    int c = blockIdx.x / NCH2;
    int ch = blockIdx.x % NCH2;
    int cnt_c = cur1[c * CPAD]; if (cnt_c > CAPC) cnt_c = CAPC;
    int s = ch * S2C;
    int n = cnt_c - s; if (n > S2C) n = S2C;
    if (n <= 0) return;                    // uniform per block
    int tid = threadIdx.x;
    size_t base = (size_t)c * CAPC + s;
    int2 e[13];
    int rk[13];

    if (tid < NF) h[tid] = 0;
    __syncthreads();
    #pragma unroll
    for (int k = 0; k < 13; k++) {         // stage + histogram + rank (merged)
        int i = tid + k * 256;
        if (i < n) {
            e[k] = X[base + i];
            rk[k] = atomicAdd(&h[e[k].x >> 24], 1);   // fine6 = lr12 >> 6
        } else e[k].x = -1;                           // x >= 0 for valid
    }
    __syncthreads();
    if (tid == 0) {
        int acc = 0;
        for (int i = 0; i < NF; i++) { ls[i] = acc; acc += h[i]; }
    }
    if (tid < NF) gb[tid] = h[tid] ? atomicAdd(&cur2[c * NF + tid], h[tid]) : 0;
    __syncthreads();
    #pragma unroll
    for (int k = 0; k < 13; k++) {         // placement: NO atomics
        if (e[k].x >= 0) {
            int f = e[k].x >> 24;
            int slot = ls[f] + rk[k];
            int2 q;
            q.x = ((e[k].x & 0x3FFFF) << 7) | ((e[k].x >> 18) & 63);  // col<<7|lr6
            q.y = e[k].y;
            buf[slot] = q;
            bk[slot] = (unsigned char)f;
        }
    }
    __syncthreads();
    for (int j = tid; j < n; j += 256) {   // coalesced flush (runs ~52 entries)
        int f = bk[j];
        int o = gb[f] + j - ls[f];
        Y[(o < CAPF) ? ((size_t)(c * NF + f) * CAPF + o)
                     : ((size_t)NBUK * CAPF)] = buf[j];
    }
}

// ---------- init A = bf16(concat(user,item)), 8 elems/thread (G13) ----------
__global__ void lgcn_init_A(const float* __restrict__ user_emb,
                            const float* __restrict__ item_emb,
                            unsigned short* __restrict__ A) {
    int i = blockIdx.x * blockDim.x + threadIdx.x;   // 8-elem group
    if (i < NELEM / 8) {
        const float4* src = (i < (N_USERS * D) / 8)
            ? (const float4*)user_emb + 2 * (size_t)i
            : (const float4*)item_emb + 2 * (size_t)(i - (N_USERS * D) / 8);
        float4 a = src[0], b = src[1];
        uint4 w;
        w.x = (unsigned)f2bf(a.x) | ((unsigned)f2bf(a.y) << 16);
        w.y = (unsigned)f2bf(a.z) | ((unsigned)f2bf(a.w) << 16);
        w.z = (unsigned)f2bf(b.x) | ((unsigned)f2bf(b.y) << 16);
        w.w = (unsigned)f2bf(b.z) | ((unsigned)f2bf(b.w) << 16);
        ((uint4*)A)[i] = w;
    }
}

// ---------- fused: per-bucket row sort + CSR emit + sorted-Y writeback +
//            SpMM layer 1 computed from LDS pairs (wave owns 16 rows) --------
__global__ void __launch_bounds__(256)
lgcn_spmm_sort(int2* __restrict__ Y,
               const int* __restrict__ cur2,
               int* __restrict__ row_ptr,
               int* __restrict__ row_cnt,
               const unsigned short* __restrict__ cur,
               unsigned short* __restrict__ nxt) {
    __shared__ int2 buf[CAPF + 2];     // 25.6 KB -> 6 blocks/CU
    __shared__ int  h[RPB];
    __shared__ int  base[RPB];
    int tid = threadIdx.x;
    int fb = blockIdx.x;
    size_t start = (size_t)fb * CAPF;
    int cnt = cur2[fb]; if (cnt > CAPF) cnt = CAPF;

    // register-stage load + per-row histogram + rank (merged, single pass)
    int2 e[13];                        // ceil(3200/256) = 13
    int rk[13];
    if (tid < RPB) h[tid] = 0;
    __syncthreads();
    #pragma unroll
    for (int k = 0; k < 13; k++) {
        int i = tid + k * 256;
        if (i < cnt) {
            e[k] = Y[start + i];
            rk[k] = atomicAdd(&h[e[k].x & 63], 1);
        } else e[k].x = -1;            // valid x >= 0 (25-bit)
    }
    __syncthreads();

    // exclusive scan of h[0..63]
    int v = (tid < RPB) ? h[tid] : 0;
    int sum = v;
    #pragma unroll
    for (int off = 1; off < RPB; off <<= 1) {
        if (tid < RPB) base[tid] = sum;
        __syncthreads();
        if (tid >= off && tid < RPB) sum += base[tid - off];
        __syncthreads();
    }
    if (tid < RPB) {
        int excl = sum - v;
        base[tid] = excl;
        int gr = (fb >> 6) * CROWS + (fb & 63) * RPB + tid;
        if (gr < N_TOTAL) {
            row_ptr[gr] = (int)start + excl;
            row_cnt[gr] = v;
        }
        // h NOT reset: h[lr] survives as row count for the compute phase
    }
    __syncthreads();

    // place regs -> row-sorted LDS (no atomics)
    #pragma unroll
    for (int k = 0; k < 13; k++) {
        if (e[k].x >= 0) {
            int lr = e[k].x & 63;
            buf[base[lr] + rk[k]] = e[k];
        }
    }
    __syncthreads();

    // coalesced sorted writeback (layer 2 reads this)
    for (int i = tid; i < cnt; i += 256) Y[start + i] = buf[i];

    // ---- SpMM layer 1 from LDS pairs: wave w owns rows w*16 .. w*16+15 ----
    int wave = tid >> 6, lane = tid & 63;
    int halfid = lane >> 5, hl = lane & 31;
    const char* __restrict__ curb = (const char*)cur + hl * 4;
    for (int lr = wave * 16; lr < wave * 16 + 16; lr++) {
        int rs = base[lr];
        int rc = h[lr];                // row count (preserved)
        float sA = 0.f, sB = 0.f;
        int jj = 0;
        for (; jj + 8 <= rc; jj += 8) {            // unguarded dual-edge bodies
            #pragma unroll
            for (int k = 0; k < 4; k++) {
                int2 q = buf[rs + jj + 2 * k + halfid];   // ds_read broadcast
                float v2 = __int_as_float(q.y);
                unsigned off = (unsigned)q.x & 0xFFFFFF80u;
                unsigned u = *(const unsigned*)(curb + off);
                sA = fmaf(v2, __uint_as_float(u << 16), sA);
                sB = fmaf(v2, __uint_as_float(u & 0xFFFF0000u), sB);
            }
        }
        for (; jj < rc; jj += 2) {                 // guarded tail (<=4 iters)
            int2 q = buf[rs + jj + halfid];        // may overread 1 (padded)
            float v2 = __int_as_float(q.y);
            unsigned off = (unsigned)q.x & 0xFFFFFF80u;
            if (jj + halfid >= rc) { v2 = 0.f; off = 0; }
            unsigned u = *(const unsigned*)(curb + off);
            sA = fmaf(v2, __uint_as_float(u << 16), sA);
            sB = fmaf(v2, __uint_as_float(u & 0xFFFF0000u), sB);
        }
        sA += __shfl_xor(sA, 32, 64);
        sB += __shfl_xor(sB, 32, 64);
        int gr = (fb >> 6) * CROWS + (fb & 63) * RPB + lr;
        if (halfid == 0 && gr < N_TOTAL) {
            unsigned int lo = f2bf(sA);
            unsigned int hi = f2bf(sB);
            ((unsigned int*)nxt)[gr * 32 + hl] = lo | (hi << 16);
        }
    }
}

// ---------- SpMM: wave per row, dual-edge, LDS-staged, 16-edge unroll ----------
__global__ void __launch_bounds__(256)
lgcn_spmm_csr(const int2* __restrict__ pairs,
              const int*  __restrict__ row_ptr,
              const int*  __restrict__ row_cnt,
              const unsigned short* __restrict__ cur,
              unsigned short* __restrict__ nxt) {
    __shared__ int2 stage[4][64];
    int t = blockIdx.x * blockDim.x + threadIdx.x;
    int r = t >> 6;
    int lane = t & 63;
    if (r >= N_TOTAL) return;
    int halfid = lane >> 5;
    int hl = lane & 31;
    const char* __restrict__ curb = (const char*)cur + hl * 4;  // lane-folded
    int2* st = stage[threadIdx.x >> 6];
    int start = row_ptr[r];
    int cnt   = row_cnt[r];
    float sA = 0.f, sB = 0.f;
    for (int base = 0; base < cnt; base += 64) {
        int idx = base + lane;
        int2 p = {0, 0};
        if (idx < cnt) p = pairs[start + idx];     // coalesced dwordx2
        st[lane] = p;                              // per-wave slice, no barrier
        int m = cnt - base; if (m > 64) m = 64;
        for (int jj = 0; jj < m; jj += 16) {       // 16 edges per body
            #pragma unroll
            for (int k = 0; k < 8; k++) {
                int2 q = st[jj + 2 * k + halfid];  // ds_read_b64 broadcast
                float v = __int_as_float(q.y);     // 0 beyond cnt
                unsigned off = (unsigned)q.x & 0xFFFFFF80u;   // col*128
                unsigned u = *(const unsigned*)(curb + off);
                sA = fmaf(v, __uint_as_float(u << 16), sA);
                sB = fmaf(v, __uint_as_float(u & 0xFFFF0000u), sB);
            }
        }
    }
    sA += __shfl_xor(sA, 32, 64);
    sB += __shfl_xor(sB, 32, 64);
    if (halfid == 0) {
        unsigned int lo = f2bf(sA);
        unsigned int hi = f2bf(sB);
        ((unsigned int*)nxt)[r * 32 + hl] = lo | (hi << 16);  // half-wave 128B
    }
}

// ---------- layer 3 at sampled rows only: e3[s,:] = (A @ E2)[row(s),:] (f32) ----
__global__ void __launch_bounds__(256)
lgcn_spmm_sampled(const int2* __restrict__ pairs,
                  const int*  __restrict__ row_ptr,
                  const int*  __restrict__ row_cnt,
                  const unsigned short* __restrict__ cur,
                  const int* __restrict__ users,
                  const int* __restrict__ items,
                  float* __restrict__ e3) {
    __shared__ int2 stage[4][64];
    int t = blockIdx.x * blockDim.x + threadIdx.x;
    int s = t >> 6;
    int lane = t & 63;
    if (s >= 2 * BATCH) return;
    int r = (s < BATCH) ? users[s] : (N_USERS + items[s - BATCH]);
    const char* __restrict__ curb = (const char*)cur + lane * 2;  // bf16 dim
    int2* st = stage[threadIdx.x >> 6];
    int start = row_ptr[r];
    int cnt   = row_cnt[r];
    float sum0 = 0.f, sum1 = 0.f;
    for (int base = 0; base < cnt; base += 64) {
        int idx = base + lane;
        int2 p = {0, 0};
        if (idx < cnt) p = pairs[start + idx];
        st[lane] = p;
        int m = cnt - base; if (m > 64) m = 64;
        for (int j = 0; j < m; j += 16) {
            #pragma unroll
            for (int k = 0; k < 16; k++) {
                int2 q = st[j + k];                // broadcast
                float v = __int_as_float(q.y);     // 0 beyond cnt
                unsigned off = (unsigned)q.x & 0xFFFFFF80u;
                unsigned short u = *(const unsigned short*)(curb + off);
                if (k & 1) sum1 = fmaf(v, bf2f(u), sum1);
                else       sum0 = fmaf(v, bf2f(u), sum0);
            }
        }
    }
    e3[s * D + lane] = sum0 + sum1;
}

// ---------- dot: gamma = <E0+E1+E2+E3>_u . <E0+E1+E2+E3>_i / 16 ----------
__global__ void lgcn_dot(const float* __restrict__ user_emb,
                         const float* __restrict__ item_emb,
                         const unsigned short* __restrict__ E1,
                         const unsigned short* __restrict__ E2,
                         const float* __restrict__ e3,
                         const int* __restrict__ users,
                         const int* __restrict__ items,
                         float* __restrict__ out) {
    int t = blockIdx.x * blockDim.x + threadIdx.x;
    int b = t >> 6;
    int d = t & 63;
    if (b < BATCH) {
        int u  = users[b];
        int it = items[b];
        int ur = u * D + d;
        int ir = (N_USERS + it) * D + d;
        float au = user_emb[ur] + bf2f(E1[ur]) + bf2f(E2[ur]) + e3[b * D + d];
        float ai = item_emb[it * D + d] + bf2f(E1[ir]) + bf2f(E2[ir])
                 + e3[(BATCH + b) * D + d];
        float p = au * ai;
        #pragma unroll
        for (int off = 32; off; off >>= 1) p += __shfl_down(p, off, 64);
        if (d == 0) out[b] = p * (1.0f / 16.0f);
    }
}

// ---------- round-1 fallback (atomic scatter) if ws too small ----------
__global__ void lgcn_init_fb(const float* __restrict__ user_emb,
                             const float* __restrict__ item_emb,
                             float* __restrict__ acc,
                             float* __restrict__ cur,
                             float* __restrict__ nxt) {
    int i = blockIdx.x * blockDim.x + threadIdx.x;
    if (i < NELEM) {
        float v = (i < N_USERS * D) ? user_emb[i] : item_emb[i - N_USERS * D];
        acc[i] = v; cur[i] = v; nxt[i] = 0.0f;
    }
}
__global__ void lgcn_spmm_fb(const int* __restrict__ rows,
                             const int* __restrict__ cols,
                             const float* __restrict__ vals,
                             const float* __restrict__ cur,
                             float* __restrict__ nxt) {
    long long t = (long long)blockIdx.x * blockDim.x + threadIdx.x;
    int e = (int)(t >> 6);
    int d = (int)(t & 63);
    if (e < NNZ) {
        float x = cur[cols[e] * D + d];
        unsafeAtomicAdd(&nxt[rows[e] * D + d], vals[e] * x);
    }
}
__global__ void lgcn_accum_fb(float* __restrict__ acc,
                              const float* __restrict__ src,
                              float* __restrict__ to_zero) {
    int i = blockIdx.x * blockDim.x + threadIdx.x;
    if (i < NELEM) {
        acc[i] += src[i];
        if (to_zero) to_zero[i] = 0.0f;
    }
}
__global__ void lgcn_dot_fb(const float* __restrict__ acc,
                            const int* __restrict__ users,
                            const int* __restrict__ items,
                            float* __restrict__ out) {
    int t = blockIdx.x * blockDim.x + threadIdx.x;
    int b = t >> 6;
    int d = t & 63;
    if (b < BATCH) {
        int u  = users[b];
        int it = items[b];
        float p = acc[u * D + d] * acc[(N_USERS + it) * D + d];
        #pragma unroll
        for (int off = 32; off; off >>= 1) p += __shfl_down(p, off, 64);
        if (d == 0) out[b] = p * (1.0f / 16.0f);
    }
}

extern "C" void kernel_launch(void* const* d_in, const int* in_sizes, int n_in,
                              void* d_out, int out_size, void* d_ws, size_t ws_size,
                              hipStream_t stream) {
    const float* user_emb = (const float*)d_in[0];
    const float* item_emb = (const float*)d_in[1];
    const int*   edge_row = (const int*)d_in[2];
    const int*   edge_col = (const int*)d_in[3];
    const float* edge_val = (const float*)d_in[4];
    const int*   users    = (const int*)d_in[5];
    const int*   items    = (const int*)d_in[6];
    float*       out      = (float*)d_out;

    const int TPB = 256;
    int init_blocks  = (NELEM + TPB - 1) / TPB;
    int init8_blocks = (NELEM / 8 + TPB - 1) / TPB;
    int spmm_blocks = (N_TOTAL * 64 + TPB - 1) / TPB;       // wave per row
    int samp_blocks = (2 * BATCH * 64 + TPB - 1) / TPB;     // wave per sampled row
    int dot_blocks  = (BATCH * 64 + TPB - 1) / TPB;

    // workspace layout (~121.5MB, proven family):
    //   X (coarse pairs, +1 sink) — dead after pass 2; A,B,C bf16 ALL alias it
    //     (CAPC sized so X bytes >= 3*NELEM*2 = 57.6MB)
    //   Y (fine pairs, +1 sink)   — row-sorted in the fused kernel
    //   e3 f32, cursors (cur1 line-padded), row_ptr/row_cnt
    int2* X = (int2*)d_ws;                              // NC*CAPC + 1
    int2* Y = X + (size_t)NC * CAPC + 1;                // NBUK*CAPF + 1
    float* e3 = (float*)(Y + (size_t)NBUK * CAPF + 1);  // 2*BATCH*D
    int* cur1 = (int*)(e3 + 2 * BATCH * D);             // NC*CPAD
    int* cur2 = cur1 + NC * CPAD;                       // NBUK
    int* row_ptr = cur2 + NBUK;                         // NBUK*RPB
    int* row_cnt = row_ptr + NBUK * RPB;                // NBUK*RPB
    size_t req = (size_t)((char*)(row_cnt + NBUK * RPB) - (char*)d_ws);
    unsigned short* A = (unsigned short*)X;             // alias: init after pass 2
    unsigned short* B = A + NELEM;                      // alias
    unsigned short* C = B + NELEM;                      // alias: 57.6MB <= X bytes

    if (ws_size < req && ws_size >= (size_t)3 * NELEM * 4) {
        // fallback: round-1 atomic path (needs only 3*NELEM floats)
        float* acc = (float*)d_ws;
        float* Af  = acc + NELEM;
        float* Bf  = Af + NELEM;
        long long st = (long long)NNZ * 64;
        int sb = (int)((st + TPB - 1) / TPB);
        lgcn_init_fb<<<init_blocks, TPB, 0, stream>>>(user_emb, item_emb, acc, Af, Bf);
        lgcn_spmm_fb<<<sb, TPB, 0, stream>>>(edge_row, edge_col, edge_val, Af, Bf);
        lgcn_accum_fb<<<init_blocks, TPB, 0, stream>>>(acc, Bf, Af);
        lgcn_spmm_fb<<<sb, TPB, 0, stream>>>(edge_row, edge_col, edge_val, Bf, Af);
        lgcn_accum_fb<<<init_blocks, TPB, 0, stream>>>(acc, Af, Bf);
        lgcn_spmm_fb<<<sb, TPB, 0, stream>>>(edge_row, edge_col, edge_val, Af, Bf);
        lgcn_accum_fb<<<init_blocks, TPB, 0, stream>>>(acc, Bf, nullptr);
        lgcn_dot_fb<<<dot_blocks, TPB, 0, stream>>>(acc, users, items, out);
        return;
    }

    // two-level radix binning (LDS-sorted, coalesced flush, single atomic pass)
    lgcn_zero<<<1, TPB, 0, stream>>>(cur1, cur2);
    lgcn_scatter1<<<S1EB, TPB, 0, stream>>>(edge_row, edge_col, edge_val, cur1, X);
    lgcn_scatter2<<<NC * NCH2, TPB, 0, stream>>>(X, cur1, cur2, Y);

    // E0 bf16 (A aliases dead X region)
    lgcn_init_A<<<init8_blocks, TPB, 0, stream>>>(user_emb, item_emb, A);

    // fused: row sort + CSR emit + sorted-Y writeback + layer 1 from LDS
    lgcn_spmm_sort<<<NBUK, TPB, 0, stream>>>(Y, cur2, row_ptr, row_cnt, A, B);

    // layer 2 full width (bf16); layer 3 only at sampled rows (f32)
    lgcn_spmm_csr<<<spmm_blocks, TPB, 0, stream>>>(Y, row_ptr, row_cnt, B, C);
    lgcn_spmm_sampled<<<samp_blocks, TPB, 0, stream>>>(Y, row_ptr, row_cnt, C,
                                                       users, items, e3);

    // gamma
    lgcn_dot<<<dot_blocks, TPB, 0, stream>>>(user_emb, item_emb, B, C, e3,
                                             users, items, out);
}